// Round 6
// baseline (1076.163 us; speedup 1.0000x reference)
//
#include <hip/hip_runtime.h>

typedef unsigned short u16;
typedef unsigned int   u32;

#define NB  16
#define NC  256
#define NH  80
#define NW  80
#define NHW 6400

typedef short bf16x8 __attribute__((ext_vector_type(8)));
typedef float f32x4  __attribute__((ext_vector_type(4)));

__device__ __forceinline__ float b2f(u16 u) {
  union { u32 i; float f; } c; c.i = ((u32)u) << 16; return c.f;
}
__device__ __forceinline__ u16 f2b(float f) {
  union { float f; u32 i; } c; c.f = f;
  return (u16)((c.i + 0x7FFFu + ((c.i >> 16) & 1u)) >> 16);
}
// dtype-dispatched input load (flag=1: f32, flag=0: bf16)
__device__ __forceinline__ float ldx(const void* p, size_t i, int f32f) {
  return f32f ? ((const float*)p)[i] : b2f(((const u16*)p)[i]);
}
// resolve dtype flag: host-decided (fh>=0) or device-probed fallback
__device__ __forceinline__ int getf(int fh, const int* flagp) {
  return (fh >= 0) ? fh : *flagp;
}

// ---- K0a (fallback only): fast parallel dtype probe ----
__global__ void probe_init(int* __restrict__ flag) { flag[0] = 0; flag[1] = 0; }

__global__ __launch_bounds__(256) void probe_count(const u16* __restrict__ x,
                                                   int* __restrict__ flag)
{
  __shared__ int cnt[256];
  int base = (blockIdx.x * 256 + threadIdx.x) * 16;   // 64*256*16 = 262144
  int c = 0;
  uint4 v0 = *(const uint4*)(x + base);
  uint4 v1 = *(const uint4*)(x + base + 8);
  u32 w[8] = {v0.x, v0.y, v0.z, v0.w, v1.x, v1.y, v1.z, v1.w};
  #pragma unroll
  for (int j = 0; j < 8; j++) {
    if (((w[j] >> 7)  & 0xFFu) == 0xFFu) c++;
    if (((w[j] >> 23) & 0xFFu) == 0xFFu) c++;
  }
  cnt[threadIdx.x] = c; __syncthreads();
  for (int s = 128; s > 0; s >>= 1) {
    if (threadIdx.x < s) cnt[threadIdx.x] += cnt[threadIdx.x + s];
    __syncthreads();
  }
  if (threadIdx.x == 0) atomicAdd(&flag[1], cnt[0]);
}

__global__ void probe_decide(int* __restrict__ flag) {
  flag[0] = (flag[1] > 16) ? 1 : 0;
}

// ---- K0b: convert all 18 weight/bias arrays into one f32 table ----
struct CvtArgs { const void* src[18]; int cum[19]; };

__global__ __launch_bounds__(256) void cvt_weights(CvtArgs a, float* __restrict__ dst,
                                                   int fh, const int* __restrict__ flagp)
{
  int f = getf(fh, flagp);
  int i = blockIdx.x * 256 + threadIdx.x;     // < 153600
  int s = 0;
  while (i >= a.cum[s + 1]) s++;
  int j = i - a.cum[s];
  float v = f ? ((const float*)a.src[s])[j] : b2f(((const u16*)a.src[s])[j]);
  if (!(v == v) || fabsf(v) > 1e30f) v = 0.f;  // scrub
  dst[i] = v;
}

// ---- K0c: split w_in / w_out into bf16 hi+lo pairs for MFMA.
// WB layout: [mat][set][256 o][256 k] u16, mat stride 131072, set stride 65536.
__global__ __launch_bounds__(256) void split_w(const float* __restrict__ w_in,
    const float* __restrict__ w_out, u16* __restrict__ WB)
{
  int i = blockIdx.x * 256 + threadIdx.x;   // < 131072
  int mat = i >> 16, idx = i & 65535;
  float v = (mat ? w_out : w_in)[idx];
  u16 hi = f2b(v);
  u16 lo = f2b(v - b2f(hi));
  WB[mat * 131072 + idx] = hi;
  WB[mat * 131072 + 65536 + idx] = lo;
}

// ---- K1: per-pixel LN stats (mean, rstd) over C; 4 px/thread vectorized ----
__global__ __launch_bounds__(256) void ln_stats(const void* __restrict__ xsrc,
    size_t xoff, int fh, const int* __restrict__ flagp, float2* __restrict__ stats)
{
  int f = getf(fh, flagp);
  int bl = blockIdx.y;
  int p4 = blockIdx.x * 1024 + threadIdx.x * 4;
  if (p4 >= NHW) return;                       // last block covers 256 px only
  size_t base = xoff + (size_t)bl * NC * NHW + p4;
  float s1[4] = {0.f, 0.f, 0.f, 0.f}, s2[4] = {0.f, 0.f, 0.f, 0.f};
  if (f) {
    const float* xp = (const float*)xsrc + base;
    for (int c = 0; c < NC; c++) {
      float4 v = *(const float4*)(xp + (size_t)c * NHW);
      s1[0] += v.x; s2[0] += v.x * v.x;
      s1[1] += v.y; s2[1] += v.y * v.y;
      s1[2] += v.z; s2[2] += v.z * v.z;
      s1[3] += v.w; s2[3] += v.w * v.w;
    }
  } else {
    const u16* xp = (const u16*)xsrc + base;
    for (int c = 0; c < NC; c++) {
      ushort4 v = *(const ushort4*)(xp + (size_t)c * NHW);
      float a = b2f(v.x), b = b2f(v.y), cc = b2f(v.z), d = b2f(v.w);
      s1[0] += a;  s2[0] += a * a;
      s1[1] += b;  s2[1] += b * b;
      s1[2] += cc; s2[2] += cc * cc;
      s1[3] += d;  s2[3] += d * d;
    }
  }
  float2* so = stats + (size_t)bl * NHW + p4;
  #pragma unroll
  for (int j = 0; j < 4; j++) {
    float mean = s1[j] * (1.f / 256.f);
    float var  = s2[j] * (1.f / 256.f) - mean * mean;
    so[j] = make_float2(mean, rsqrtf(var + 1e-5f));
  }
}

// ---- K2: fused LN + BOTH depthwise convs, register-blocked stencil ----
__global__ __launch_bounds__(256) void dw_both(const void* __restrict__ xsrc,
    size_t xoff, int fh, const int* __restrict__ flagp,
    const float2* __restrict__ stats,
    const float* __restrict__ g, const float* __restrict__ bt,
    const float* __restrict__ wx7,  const float* __restrict__ bx7,
    const float* __restrict__ wx11, const float* __restrict__ bx11,
    const float* __restrict__ wx21, const float* __restrict__ bx21,
    const float* __restrict__ wy7,  const float* __restrict__ by7,
    const float* __restrict__ wy11, const float* __restrict__ by11,
    const float* __restrict__ wy21, const float* __restrict__ by21,
    u16* __restrict__ sx, u16* __restrict__ sy)
{
  __shared__ float xnp[80][116];        // cols 0..15 & 96..111 zero halo
  __shared__ float cwx[21], cwy[21];
  __shared__ float cbs[2];
  int f = getf(fh, flagp);
  int bc = blockIdx.x;                  // bl*256 + c
  int c  = bc & 255;
  int bl = bc >> 8;
  int t = threadIdx.x;
  if (t < 21) {
    float v = wx21[c * 21 + t];
    if (t >= 5 && t <= 15) v += wx11[c * 11 + t - 5];
    if (t >= 7 && t <= 13) v += wx7[c * 7 + t - 7];
    cwx[t] = v;
  } else if (t < 42) {
    int j = t - 21;
    float v = wy21[c * 21 + j];
    if (j >= 5 && j <= 15) v += wy11[c * 11 + j - 5];
    if (j >= 7 && j <= 13) v += wy7[c * 7 + j - 7];
    cwy[j] = v;
  } else if (t == 42) { cbs[0] = bx7[c] + bx11[c] + bx21[c]; }
  else if (t == 43)   { cbs[1] = by7[c] + by11[c] + by21[c]; }
  // zero halo columns (80 rows x 32 cols)
  for (int i = t; i < 2560; i += 256) {
    int rr = i >> 5, cc = i & 31;
    xnp[rr][cc < 16 ? cc : 80 + cc] = 0.f;
  }
  float cg = g[c], cbt = bt[c];
  size_t xrow = xoff + (size_t)bc * NHW;
  const float2* st = stats + (size_t)bl * NHW;
  for (int i = t; i < NHW; i += 256) {
    float v = ldx(xsrc, xrow + i, f);
    float2 s = st[i];
    xnp[i / 80][16 + i % 80] = (v - s.x) * s.y * cg + cbt;
  }
  __syncthreads();
  float bxv = cbs[0], byv = cbs[1];
  size_t obase = (size_t)bc * NHW;
  for (int u = t; u < 800; u += 256) {  // 3 full rounds + 32-thread tail
    int h = u / 10, w0 = (u % 10) * 8;
    float r[32];
    #pragma unroll
    for (int j = 0; j < 8; j++)
      *(float4*)&r[4 * j] = *(const float4*)&xnp[h][w0 + 4 + 4 * j];
    float ax[8], ay[8];
    #pragma unroll
    for (int j = 0; j < 8; j++) { ax[j] = bxv; ay[j] = byv; }
    #pragma unroll
    for (int dd = 0; dd < 21; dd++) {
      float wv = cwx[dd];
      #pragma unroll
      for (int j = 0; j < 8; j++) ax[j] += wv * r[j + 2 + dd];
    }
    #pragma unroll
    for (int dd = 0; dd < 21; dd++) {
      int hp = h + dd - 10;
      int hc = min(max(hp, 0), 79);
      float wv = (hp == hc) ? cwy[dd] : 0.f;
      float4 v0 = *(const float4*)&xnp[hc][16 + w0];
      float4 v1 = *(const float4*)&xnp[hc][20 + w0];
      ay[0] += wv * v0.x; ay[1] += wv * v0.y; ay[2] += wv * v0.z; ay[3] += wv * v0.w;
      ay[4] += wv * v1.x; ay[5] += wv * v1.y; ay[6] += wv * v1.z; ay[7] += wv * v1.w;
    }
    size_t ob = obase + h * 80 + w0;
    ushort4 a0, a1, b0, b1;
    a0.x = f2b(ax[0]); a0.y = f2b(ax[1]); a0.z = f2b(ax[2]); a0.w = f2b(ax[3]);
    a1.x = f2b(ax[4]); a1.y = f2b(ax[5]); a1.z = f2b(ax[6]); a1.w = f2b(ax[7]);
    b0.x = f2b(ay[0]); b0.y = f2b(ay[1]); b0.z = f2b(ay[2]); b0.w = f2b(ay[3]);
    b1.x = f2b(ay[4]); b1.y = f2b(ay[5]); b1.z = f2b(ay[6]); b1.w = f2b(ay[7]);
    *(ushort4*)(sx + ob)     = a0;
    *(ushort4*)(sx + ob + 4) = a1;
    *(ushort4*)(sy + ob)     = b0;
    *(ushort4*)(sy + ob + 4) = b1;
  }
}

// ---- K3/K8: MFMA pointwise conv. C[o][p] = sum_k W[o][k]*In[k][p], W split
// into bf16 hi+lo. One block = full 256 o x 64 px strip of one batch.
// Round-6 changes:
//  (a) InT swizzle f(px) = (px ^ (px>>3)) & 7 on BOTH write and read — the old
//      f = px&7 collapsed to a constant across each 8-lane store group
//      (8-way ds_write conflict, 4.9M conflict-cycles/dispatch).
//  (b) T14 async-STAGE for W panels: chunk ch+1's global loads are issued at
//      the top of iteration ch (latency hides under ds_reads + 32 MFMAs);
//      the LDS write happens after the post-MFMA barrier.
// FINAL=1: out = acc + 2*bias + x, dtype-dispatched; else in-place bf16 + bias.
template<int FINAL>
__global__ __launch_bounds__(256) void pw_mfma_t(const u16* __restrict__ WB,
    u16* io0, u16* io1, const float* __restrict__ bias,
    void* __restrict__ OutBase, size_t out_off,
    const void* __restrict__ xsrc, size_t xoff,
    int fh, const int* __restrict__ flagp)
{
  __shared__ u16 S[32768];              // 64 KB: InT = S[0:16384], Wp = S[16384:]
  u16* InT = S;
  u16* Wp  = S + 16384;
  int bl = blockIdx.y;
  int p0 = blockIdx.x * 64;
  int t  = threadIdx.x;
  int lane = t & 63, wid = t >> 6, lg = lane >> 4, lr = lane & 15;
  u16* io = (FINAL || blockIdx.z == 0) ? io0 : io1;

  // ---- W chunk-0 prefetch into regs (overlaps with In staging) ----
  int wo = t >> 3, sg = t & 7;
  const u16* wsrc = WB + (sg >> 2) * 65536 + (sg & 3) * 8;
  uint4 wreg[8];
  #pragma unroll
  for (int rep = 0; rep < 8; rep++)
    wreg[rep] = *(const uint4*)(wsrc + (rep * 32 + wo) * 256);

  // ---- stage InT with register 8x8 transpose; swizzled writes ----
  {
    int kb = t >> 3, pb = t & 7;
    const u16* src = io + (size_t)bl * NC * NHW + p0 + pb * 8;
    u32 r[8][4];
    #pragma unroll
    for (int i = 0; i < 8; i++) {
      uint4 v = *(const uint4*)(src + (size_t)(kb * 8 + i) * NHW);
      r[i][0] = v.x; r[i][1] = v.y; r[i][2] = v.z; r[i][3] = v.w;
    }
    #pragma unroll
    for (int j = 0; j < 8; j++) {
      u32 w[4];
      #pragma unroll
      for (int m = 0; m < 4; m++) {
        u32 a = r[2 * m][j >> 1], b = r[2 * m + 1][j >> 1];
        w[m] = (j & 1) ? ((a >> 16) | (b & 0xFFFF0000u))
                       : ((a & 0xFFFFu) | (b << 16));
      }
      int p = pb * 8 + j;
      *(uint4*)&InT[p * 256 + ((kb ^ ((j ^ pb) & 7)) * 8)] = make_uint4(w[0], w[1], w[2], w[3]);
    }
  }
  // ---- write W chunk 0 to Wp; one barrier covers InT + Wp ----
  #pragma unroll
  for (int rep = 0; rep < 8; rep++) {
    int o = rep * 32 + wo;
    *(uint4*)&Wp[o * 64 + ((sg ^ (o & 7)) * 8)] = wreg[rep];
  }
  __syncthreads();

  f32x4 acc[4][4];
  #pragma unroll
  for (int m = 0; m < 4; m++)
    #pragma unroll
    for (int n = 0; n < 4; n++)
      acc[m][n] = (f32x4){0.f, 0.f, 0.f, 0.f};

  for (int ch = 0; ch < 8; ch++) {
    // issue next chunk's W loads early (T14: hide under ds_reads + MFMAs)
    if (ch < 7) {
      #pragma unroll
      for (int rep = 0; rep < 8; rep++)
        wreg[rep] = *(const uint4*)(wsrc + (rep * 32 + wo) * 256 + (ch + 1) * 32);
    }
    bf16x8 bfr[4];
    #pragma unroll
    for (int n = 0; n < 4; n++) {
      int px = n * 16 + lr;
      int fpx = (px ^ (px >> 3)) & 7;
      bfr[n] = *(const bf16x8*)&InT[px * 256 + (((ch * 4 + lg) ^ fpx) * 8)];
    }
    #pragma unroll
    for (int m = 0; m < 4; m++) {
      int o = (wid * 4 + m) * 16 + lr;
      bf16x8 ahi = *(const bf16x8*)&Wp[o * 64 + ((lg ^ (o & 7)) * 8)];
      bf16x8 alo = *(const bf16x8*)&Wp[o * 64 + (((4 + lg) ^ (o & 7)) * 8)];
      #pragma unroll
      for (int n = 0; n < 4; n++) {
        acc[m][n] = __builtin_amdgcn_mfma_f32_16x16x32_bf16(ahi, bfr[n], acc[m][n], 0, 0, 0);
        acc[m][n] = __builtin_amdgcn_mfma_f32_16x16x32_bf16(alo, bfr[n], acc[m][n], 0, 0, 0);
      }
    }
    __syncthreads();                    // Wp readers for ch done
    if (ch < 7) {
      #pragma unroll
      for (int rep = 0; rep < 8; rep++) {
        int o = rep * 32 + wo;
        *(uint4*)&Wp[o * 64 + ((sg ^ (o & 7)) * 8)] = wreg[rep];
      }
      __syncthreads();                  // Wp ready for ch+1
    }
  }

  // ---- epilogue via LDS round-trip for vectorized global stores ----
  if (FINAL) {
    float* Otf = (float*)S;             // [256 o][64 px] f32, swizzled
    #pragma unroll
    for (int m = 0; m < 4; m++)
      #pragma unroll
      for (int r = 0; r < 4; r++) {
        int o = (wid * 4 + m) * 16 + 4 * lg + r;
        float bv = 2.f * bias[o];
        #pragma unroll
        for (int n = 0; n < 4; n++) {
          int px = n * 16 + lr;
          Otf[o * 64 + (px ^ ((o & 7) * 8))] = acc[m][n][r] + bv;
        }
      }
    __syncthreads();
    int f = getf(fh, flagp);
    size_t gbase = ((size_t)bl * NC + t) * NHW + p0;
    #pragma unroll
    for (int j2 = 0; j2 < 16; j2++) {
      float4 v = *(float4*)&Otf[t * 64 + ((j2 * 4) ^ ((t & 7) * 8))];
      size_t gi = gbase + j2 * 4;
      if (f) {
        const float* xp = (const float*)xsrc + xoff + gi;
        v.x += xp[0]; v.y += xp[1]; v.z += xp[2]; v.w += xp[3];
        *(float4*)((float*)OutBase + out_off + gi) = v;
      } else {
        ushort4 xv = *(const ushort4*)((const u16*)xsrc + xoff + gi);
        ushort4 ov;
        ov.x = f2b(v.x + b2f(xv.x)); ov.y = f2b(v.y + b2f(xv.y));
        ov.z = f2b(v.z + b2f(xv.z)); ov.w = f2b(v.w + b2f(xv.w));
        *(ushort4*)((u16*)OutBase + out_off + gi) = ov;
      }
    }
  } else {
    u16* Ot = S;                        // [256 o][64 px] u16, swizzled
    #pragma unroll
    for (int m = 0; m < 4; m++)
      #pragma unroll
      for (int r = 0; r < 4; r++) {
        int o = (wid * 4 + m) * 16 + 4 * lg + r;
        float bv = bias[o];
        #pragma unroll
        for (int n = 0; n < 4; n++) {
          int px = n * 16 + lr;
          Ot[o * 64 + (px ^ ((o & 7) * 8))] = f2b(acc[m][n][r] + bv);
        }
      }
    __syncthreads();
    u16* orow = io + ((size_t)bl * NC + t) * NHW + p0;
    #pragma unroll
    for (int j = 0; j < 8; j++) {
      uint4 v = *(uint4*)&Ot[t * 64 + ((j ^ (t & 7)) * 8)];
      *(uint4*)(orow + j * 8) = v;
    }
  }
  (void)OutBase; (void)out_off; (void)xsrc; (void)xoff; (void)flagp; (void)io1;
}

// ---- K-T fused: per-plane 80x80 bf16 transpose + row/col sum of squares ----
__global__ __launch_bounds__(256) void transpose_sumsq(const u16* __restrict__ fx,
    const u16* __restrict__ fy, u16* __restrict__ fxT, u16* __restrict__ fyT,
    float* __restrict__ rs_fx, float* __restrict__ rs_fy,
    float* __restrict__ cs_fx, float* __restrict__ cs_fy)
{
  __shared__ u16 tile[80][81];
  int pl = blockIdx.x, ten = blockIdx.y;
  const u16* src = (ten ? fy : fx) + (size_t)pl * NHW;
  u16*       dst = (ten ? fyT : fxT) + (size_t)pl * NHW;
  int t = threadIdx.x;
  for (int i = t; i < NHW; i += 256) tile[i / 80][i % 80] = src[i];
  __syncthreads();
  for (int i = t; i < NHW; i += 256) dst[i] = tile[i % 80][i / 80];
  if (t < 80) {
    float s = 0.f;
    #pragma unroll
    for (int k = 0; k < 80; k++) { float v = b2f(tile[t][k]); s += v * v; }
    (ten ? rs_fy : rs_fx)[pl * 80 + t] = s;
  } else if (t < 160) {
    int w = t - 80; float s = 0.f;
    #pragma unroll
    for (int h = 0; h < 80; h++) { float v = b2f(tile[h][w]); s += v * v; }
    (ten ? cs_fy : cs_fx)[pl * 80 + w] = s;
  }
}

// ---- K5: combine over ci -> inverse norms ----
__global__ __launch_bounds__(256) void norm_combine(const float* __restrict__ rs_fx,
    const float* __restrict__ rs_fy, const float* __restrict__ cs_fx,
    const float* __restrict__ cs_fy, float* __restrict__ invn, int Nb)
{
  int t = blockIdx.x * 256 + threadIdx.x;   // 4*Nb*640 total
  int blk = Nb * 640;
  int side = t / blk, r = t % blk;
  int b = r / 640, rem = r % 640, hd = rem / 80, row = rem % 80;
  const float* src = (side == 0) ? rs_fy : (side == 1) ? rs_fx : (side == 2) ? cs_fx : cs_fy;
  size_t base = (size_t)(b * 256 + hd * 32) * 80 + row;
  float s = 0.f;
  #pragma unroll
  for (int ci = 0; ci < 32; ci++) s += src[base + ci * 80];
  invn[t] = 1.f / fmaxf(sqrtf(s), 1e-12f);
}

// ---- MFMA helpers for 80x80 Gram-style tiles ----
template<int T0, int NT>
__device__ __forceinline__ void gram_wave(const u16* pa, const u16* pb,
                                          int lg, int lr, f32x4* acc)
{
  constexpr int MLO = T0 / 5;
  #pragma unroll
  for (int ch = 0; ch < 3; ch++) {
    bool tz = (ch == 2) && (lg >= 2);
    int kk = ch * 32 + 8 * lg;
    if (tz) kk = 0;
    bf16x8 af[2], bf[5];
    #pragma unroll
    for (int m = 0; m < 2; m++)
      af[m] = *(const bf16x8*)(pa + ((MLO + m) * 16 + lr) * 80 + kk);
    #pragma unroll
    for (int n = 0; n < 5; n++)
      bf[n] = *(const bf16x8*)(pb + (n * 16 + lr) * 80 + kk);
    if (tz) {
      bf16x8 z = {0, 0, 0, 0, 0, 0, 0, 0};
      af[0] = z; af[1] = z;
    }
    #pragma unroll
    for (int j = 0; j < NT; j++) {
      acc[j] = __builtin_amdgcn_mfma_f32_16x16x32_bf16(
          af[(T0 + j) / 5 - MLO], bf[(T0 + j) % 5], acc[j], 0, 0, 0);
    }
  }
}

template<int T0, int NT>
__device__ __forceinline__ void gram_all(const u16* Ab, const u16* Bb,
                                         int lg, int lr, f32x4* acc)
{
  for (int ci = 0; ci < 32; ci++)
    gram_wave<T0, NT>(Ab + (size_t)ci * NHW, Bb + (size_t)ci * NHW, lg, lr, acc);
}

// ---- K6: MFMA Gram (sum over 32 ci) + cosine scale + softmax -> Sbuf ----
__global__ __launch_bounds__(256) void gram_softmax_mfma(const u16* __restrict__ fx,
    const u16* __restrict__ fy, const u16* __restrict__ fxT, const u16* __restrict__ fyT,
    const float* __restrict__ invn, u16* __restrict__ Sbuf, int Nb)
{
  __shared__ float At[80][81];
  int hd = blockIdx.x, b = blockIdx.y, axis = blockIdx.z;
  size_t sl0 = (size_t)(b * 256 + hd * 32) * NHW;
  const u16* Ab = (axis ? fxT : fy) + sl0;
  const u16* Bb = (axis ? fyT : fx) + sl0;
  int t = threadIdx.x, lane = t & 63, wid = t >> 6;
  int lg = lane >> 4, lr = lane & 15;
  f32x4 acc0 = {0.f, 0.f, 0.f, 0.f};
  f32x4 acc[7];
  #pragma unroll
  for (int j = 0; j < 7; j++) acc[j] = acc0;
  if      (wid == 0) gram_all<0, 7>(Ab, Bb, lg, lr, acc);
  else if (wid == 1) gram_all<7, 6>(Ab, Bb, lg, lr, acc);
  else if (wid == 2) gram_all<13, 6>(Ab, Bb, lg, lr, acc);
  else               gram_all<19, 6>(Ab, Bb, lg, lr, acc);
  int blk = Nb * 640;
  int rowbase = (b * 8 + hd) * 80;
  const float* invq = invn + (axis ? 2 * blk : 0)   + rowbase;
  const float* invk = invn + (axis ? 3 * blk : blk) + rowbase;
  int t0  = wid ? 6 * wid + 1 : 0;
  int cnt = wid ? 6 : 7;
  #pragma unroll
  for (int j = 0; j < 7; j++) {
    if (j < cnt) {
      int tt = t0 + j, m = tt / 5, n = tt % 5;
      int col = n * 16 + lr;
      float ik = invk[col];
      #pragma unroll
      for (int r = 0; r < 4; r++) {
        int row = m * 16 + 4 * lg + r;
        float gv = acc[j][r] * invq[row] * ik;
        At[row][col] = fminf(fmaxf(gv, -8.f), 8.f);  // |cos|<=1; NaN->-8
      }
    }
  }
  __syncthreads();
  u16* Sg = Sbuf + ((size_t)(axis * Nb * 8 + b * 8 + hd)) * NHW;
  if (t < 80) {
    float mx = -1e30f;
    for (int j = 0; j < 80; j++) mx = fmaxf(mx, At[t][j]);
    float s = 0.f;
    for (int j = 0; j < 80; j++) s += __expf(At[t][j] - mx);
    float inv = 1.f / s;
    for (int j = 0; j < 80; j++) Sg[t * 80 + j] = f2b(__expf(At[t][j] - mx) * inv);
  }
}

// ---- K7: MFMA fused H+W attention apply, IN PLACE over fx slice ----
template<int T0, int NT>
__device__ __forceinline__ void apply_wave(const u16* SH, const u16* fxT,
    const u16* fyP, const u16* SW, int lg, int lr, f32x4* acc)
{
  constexpr int MLO = T0 / 5;
  for (int ch = 0; ch < 3; ch++) {
    bool tz = (ch == 2) && (lg >= 2);
    int kk = ch * 32 + 8 * lg;
    if (tz) kk = 0;
    bf16x8 a1[2], a2[2], b1[5], b2[5];
    #pragma unroll
    for (int m = 0; m < 2; m++) {
      a1[m] = *(const bf16x8*)(SH  + ((MLO + m) * 16 + lr) * 80 + kk);
      a2[m] = *(const bf16x8*)(fyP + ((MLO + m) * 16 + lr) * 80 + kk);
    }
    #pragma unroll
    for (int n = 0; n < 5; n++) {
      b1[n] = *(const bf16x8*)(fxT + (n * 16 + lr) * 80 + kk);
      b2[n] = *(const bf16x8*)(SW  + (n * 16 + lr) * 80 + kk);
    }
    if (tz) {
      bf16x8 z = {0, 0, 0, 0, 0, 0, 0, 0};
      a1[0] = z; a1[1] = z; a2[0] = z; a2[1] = z;
    }
    #pragma unroll
    for (int j = 0; j < NT; j++) {
      acc[j] = __builtin_amdgcn_mfma_f32_16x16x32_bf16(
          a1[(T0 + j) / 5 - MLO], b1[(T0 + j) % 5], acc[j], 0, 0, 0);
      acc[j] = __builtin_amdgcn_mfma_f32_16x16x32_bf16(
          a2[(T0 + j) / 5 - MLO], b2[(T0 + j) % 5], acc[j], 0, 0, 0);
    }
  }
}

__global__ __launch_bounds__(256, 2) void apply_hw_mfma(const u16* __restrict__ fy_g,
    const u16* __restrict__ fxT_g, const u16* __restrict__ Sbuf,
    const float* __restrict__ invn, u16* fx_io, int Nb)
{
  int ci = blockIdx.x, hd = blockIdx.y, b = blockIdx.z;
  size_t off = (size_t)(b * 256 + hd * 32 + ci) * NHW;
  const u16* SgH = Sbuf + (size_t)(b * 8 + hd) * NHW;
  const u16* SgW = Sbuf + ((size_t)(Nb * 8) + b * 8 + hd) * NHW;
  const u16* fyP = fy_g + off;
  const u16* fxT = fxT_g + off;
  int t = threadIdx.x, lane = t & 63, wid = t >> 6;
  int lg = lane >> 4, lr = lane & 15;
  f32x4 acc0 = {0.f, 0.f, 0.f, 0.f};
  f32x4 acc[7];
  #pragma unroll
  for (int j = 0; j < 7; j++) acc[j] = acc0;
  if      (wid == 0) apply_wave<0, 7>(SgH, fxT, fyP, SgW, lg, lr, acc);
  else if (wid == 1) apply_wave<7, 6>(SgH, fxT, fyP, SgW, lg, lr, acc);
  else if (wid == 2) apply_wave<13, 6>(SgH, fxT, fyP, SgW, lg, lr, acc);
  else               apply_wave<19, 6>(SgH, fxT, fyP, SgW, lg, lr, acc);
  const float* invqH = invn + (b * 8 + hd) * 80;                 // H_fy(q)
  const float* invqW = invn + 2 * Nb * 640 + (b * 8 + hd) * 80;  // W_fx(q)
  int t0  = wid ? 6 * wid + 1 : 0;
  int cnt = wid ? 6 : 7;
  #pragma unroll
  for (int j = 0; j < 7; j++) {
    if (j < cnt) {
      int tt = t0 + j, m = tt / 5, n = tt % 5;
      int col = n * 16 + lr;
      float ivW = invqW[col];
      #pragma unroll
      for (int r = 0; r < 4; r++) {
        int row = m * 16 + 4 * lg + r;
        size_t ix = off + row * 80 + col;
        float v = acc[j][r] + b2f(fy_g[ix]) * invqH[row] + b2f(fx_io[ix]) * ivW;
        fx_io[ix] = f2b(v);
      }
    }
  }
}

extern "C" void kernel_launch(void* const* d_in, const int* in_sizes, int n_in,
                              void* d_out, int out_size, void* d_ws, size_t ws_size,
                              hipStream_t stream) {
  // Weight conversion table: d_in[1..18] in setup_inputs order.
  const int wsz[18] = {256, 256, 65536, 256, 65536, 256,
                       1792, 256, 2816, 256, 5376, 256,
                       1792, 256, 2816, 256, 5376, 256};
  CvtArgs ca;
  int cum = 0;
  for (int i = 0; i < 18; i++) { ca.src[i] = d_in[i + 1]; ca.cum[i] = cum; cum += wsz[i]; }
  ca.cum[18] = cum;   // 153600

  // Host-side dtype detection: x (and out) have 26,214,400 elements, so
  // 104857600 bytes => f32, 52428800 => bf16. Try in_sizes[0] AND out_size.
  // Fall back to the fast device probe only if neither matches.
  int hostf = -1;
  if (in_sizes && n_in > 0) {
    if      (in_sizes[0] == 104857600) hostf = 1;
    else if (in_sizes[0] == 52428800)  hostf = 0;
  }
  if (hostf < 0) {
    if      (out_size == 104857600) hostf = 1;
    else if (out_size == 52428800)  hostf = 0;
  }

  // ws layout: flag(16) | wbuf(614400) | wsplit(524288) | per-chunk buffers.
  int Nb = 1;
  for (int cand = 16; cand >= 1; cand >>= 1) {
    size_t need = (size_t)cand * 13701120 + 614416 + 524288;
    if (need <= ws_size) { Nb = cand; break; }
  }
  char* p = (char*)d_ws;
  int*    flag  = (int*)p;    p += 16;
  float*  wbuf  = (float*)p;  p += 614400;
  u16*    wsplit= (u16*)p;    p += 524288;     // [2 mat][2 set][256][256] bf16
  u16*    fxbuf = (u16*)p;    p += (size_t)Nb * 3276800;
  u16*    fybuf = (u16*)p;    p += (size_t)Nb * 3276800;
  u16*    fxT   = (u16*)p;    p += (size_t)Nb * 3276800;
  u16*    fyT   = (u16*)p;    p += (size_t)Nb * 3276800;
  float2* stats = (float2*)p; p += (size_t)Nb * 51200;
  float*  rs_fx = (float*)p;  p += (size_t)Nb * 81920;
  float*  rs_fy = (float*)p;  p += (size_t)Nb * 81920;
  float*  cs_fx = (float*)p;  p += (size_t)Nb * 81920;
  float*  cs_fy = (float*)p;  p += (size_t)Nb * 81920;
  float*  invn  = (float*)p;  p += (size_t)Nb * 10240;
  u16*    Sbuf  = (u16*)p;

  // f32 weight views
  float* ln_g = wbuf + ca.cum[0];  float* ln_b = wbuf + ca.cum[1];
  float* w_in = wbuf + ca.cum[2];  float* b_in = wbuf + ca.cum[3];
  float* w_out= wbuf + ca.cum[4]; float* b_out= wbuf + ca.cum[5];
  float* wx7  = wbuf + ca.cum[6];  float* bx7  = wbuf + ca.cum[7];
  float* wx11 = wbuf + ca.cum[8];  float* bx11 = wbuf + ca.cum[9];
  float* wx21 = wbuf + ca.cum[10]; float* bx21 = wbuf + ca.cum[11];
  float* wy7  = wbuf + ca.cum[12]; float* by7  = wbuf + ca.cum[13];
  float* wy11 = wbuf + ca.cum[14]; float* by11 = wbuf + ca.cum[15];
  float* wy21 = wbuf + ca.cum[16]; float* by21 = wbuf + ca.cum[17];

  if (hostf < 0) {
    probe_init<<<dim3(1), dim3(1), 0, stream>>>(flag);
    probe_count<<<dim3(64), dim3(256), 0, stream>>>((const u16*)d_in[0], flag);
    probe_decide<<<dim3(1), dim3(1), 0, stream>>>(flag);
  }
  cvt_weights<<<dim3(600), dim3(256), 0, stream>>>(ca, wbuf, hostf, flag);
  split_w<<<dim3(512), dim3(256), 0, stream>>>(w_in, w_out, wsplit);

  for (int b0 = 0; b0 < NB; b0 += Nb) {
    size_t xoff = (size_t)b0 * NC * NHW;   // element offset of chunk in x / out

    ln_stats<<<dim3(7, Nb), dim3(256), 0, stream>>>(d_in[0], xoff, hostf, flag, stats);
    dw_both<<<dim3(Nb * 256), dim3(256), 0, stream>>>(d_in[0], xoff, hostf, flag, stats,
        ln_g, ln_b, wx7, bx7, wx11, bx11, wx21, bx21,
        wy7, by7, wy11, by11, wy21, by21, fxbuf, fybuf);
    pw_mfma_t<0><<<dim3(100, Nb, 2), dim3(256), 0, stream>>>(wsplit, fxbuf, fybuf,
        b_in, nullptr, 0, nullptr, 0, hostf, flag);
    transpose_sumsq<<<dim3(Nb * 256, 2), dim3(256), 0, stream>>>(fxbuf, fybuf, fxT, fyT,
        rs_fx, rs_fy, cs_fx, cs_fy);
    norm_combine<<<dim3(10 * Nb), dim3(256), 0, stream>>>(rs_fx, rs_fy, cs_fx, cs_fy, invn, Nb);
    gram_softmax_mfma<<<dim3(8, Nb, 2), dim3(256), 0, stream>>>(fxbuf, fybuf, fxT, fyT, invn, Sbuf, Nb);
    apply_hw_mfma<<<dim3(32, 8, Nb), dim3(256), 0, stream>>>(fybuf, fxT, Sbuf, invn, fxbuf, Nb);
    pw_mfma_t<1><<<dim3(100, Nb, 1), dim3(256), 0, stream>>>(wsplit + 131072, fxbuf, nullptr,
        b_out, d_out, xoff, d_in[0], xoff, hostf, flag);
  }
  (void)in_sizes; (void)n_in; (void)out_size;
}

// Round 7
// 888.183 us; speedup vs baseline: 1.2116x; 1.2116x over previous
//
#include <hip/hip_runtime.h>

typedef unsigned short u16;
typedef unsigned int   u32;

#define NB  16
#define NC  256
#define NH  80
#define NW  80
#define NHW 6400

typedef short bf16x8 __attribute__((ext_vector_type(8)));
typedef float f32x4  __attribute__((ext_vector_type(4)));

__device__ __forceinline__ float b2f(u16 u) {
  union { u32 i; float f; } c; c.i = ((u32)u) << 16; return c.f;
}
__device__ __forceinline__ u16 f2b(float f) {
  union { float f; u32 i; } c; c.f = f;
  return (u16)((c.i + 0x7FFFu + ((c.i >> 16) & 1u)) >> 16);
}
// dtype-dispatched input load (flag=1: f32, flag=0: bf16)
__device__ __forceinline__ float ldx(const void* p, size_t i, int f32f) {
  return f32f ? ((const float*)p)[i] : b2f(((const u16*)p)[i]);
}
// resolve dtype flag: host-decided (fh>=0) or device-probed fallback
__device__ __forceinline__ int getf(int fh, const int* flagp) {
  return (fh >= 0) ? fh : *flagp;
}

// ---- K0a (fallback only): fast parallel dtype probe ----
__global__ void probe_init(int* __restrict__ flag) { flag[0] = 0; flag[1] = 0; }

__global__ __launch_bounds__(256) void probe_count(const u16* __restrict__ x,
                                                   int* __restrict__ flag)
{
  __shared__ int cnt[256];
  int base = (blockIdx.x * 256 + threadIdx.x) * 16;   // 64*256*16 = 262144
  int c = 0;
  uint4 v0 = *(const uint4*)(x + base);
  uint4 v1 = *(const uint4*)(x + base + 8);
  u32 w[8] = {v0.x, v0.y, v0.z, v0.w, v1.x, v1.y, v1.z, v1.w};
  #pragma unroll
  for (int j = 0; j < 8; j++) {
    if (((w[j] >> 7)  & 0xFFu) == 0xFFu) c++;
    if (((w[j] >> 23) & 0xFFu) == 0xFFu) c++;
  }
  cnt[threadIdx.x] = c; __syncthreads();
  for (int s = 128; s > 0; s >>= 1) {
    if (threadIdx.x < s) cnt[threadIdx.x] += cnt[threadIdx.x + s];
    __syncthreads();
  }
  if (threadIdx.x == 0) atomicAdd(&flag[1], cnt[0]);
}

__global__ void probe_decide(int* __restrict__ flag) {
  flag[0] = (flag[1] > 16) ? 1 : 0;
}

// ---- K0b: convert all 18 weight/bias arrays into one f32 table ----
struct CvtArgs { const void* src[18]; int cum[19]; };

__global__ __launch_bounds__(256) void cvt_weights(CvtArgs a, float* __restrict__ dst,
                                                   int fh, const int* __restrict__ flagp)
{
  int f = getf(fh, flagp);
  int i = blockIdx.x * 256 + threadIdx.x;     // < 153600
  int s = 0;
  while (i >= a.cum[s + 1]) s++;
  int j = i - a.cum[s];
  float v = f ? ((const float*)a.src[s])[j] : b2f(((const u16*)a.src[s])[j]);
  if (!(v == v) || fabsf(v) > 1e30f) v = 0.f;  // scrub
  dst[i] = v;
}

// ---- K0c: split w_in / w_out into bf16 hi+lo pairs for MFMA.
// WB layout: [mat][set][256 o][256 k] u16, mat stride 131072, set stride 65536.
__global__ __launch_bounds__(256) void split_w(const float* __restrict__ w_in,
    const float* __restrict__ w_out, u16* __restrict__ WB)
{
  int i = blockIdx.x * 256 + threadIdx.x;   // < 131072
  int mat = i >> 16, idx = i & 65535;
  float v = (mat ? w_out : w_in)[idx];
  u16 hi = f2b(v);
  u16 lo = f2b(v - b2f(hi));
  WB[mat * 131072 + idx] = hi;
  WB[mat * 131072 + 65536 + idx] = lo;
}

// ---- K1: per-pixel LN stats (mean, rstd) over C; 4 px/thread vectorized ----
__global__ __launch_bounds__(256) void ln_stats(const void* __restrict__ xsrc,
    size_t xoff, int fh, const int* __restrict__ flagp, float2* __restrict__ stats)
{
  int f = getf(fh, flagp);
  int bl = blockIdx.y;
  int p4 = blockIdx.x * 1024 + threadIdx.x * 4;
  if (p4 >= NHW) return;                       // last block covers 256 px only
  size_t base = xoff + (size_t)bl * NC * NHW + p4;
  float s1[4] = {0.f, 0.f, 0.f, 0.f}, s2[4] = {0.f, 0.f, 0.f, 0.f};
  if (f) {
    const float* xp = (const float*)xsrc + base;
    for (int c = 0; c < NC; c++) {
      float4 v = *(const float4*)(xp + (size_t)c * NHW);
      s1[0] += v.x; s2[0] += v.x * v.x;
      s1[1] += v.y; s2[1] += v.y * v.y;
      s1[2] += v.z; s2[2] += v.z * v.z;
      s1[3] += v.w; s2[3] += v.w * v.w;
    }
  } else {
    const u16* xp = (const u16*)xsrc + base;
    for (int c = 0; c < NC; c++) {
      ushort4 v = *(const ushort4*)(xp + (size_t)c * NHW);
      float a = b2f(v.x), b = b2f(v.y), cc = b2f(v.z), d = b2f(v.w);
      s1[0] += a;  s2[0] += a * a;
      s1[1] += b;  s2[1] += b * b;
      s1[2] += cc; s2[2] += cc * cc;
      s1[3] += d;  s2[3] += d * d;
    }
  }
  float2* so = stats + (size_t)bl * NHW + p4;
  #pragma unroll
  for (int j = 0; j < 4; j++) {
    float mean = s1[j] * (1.f / 256.f);
    float var  = s2[j] * (1.f / 256.f) - mean * mean;
    so[j] = make_float2(mean, rsqrtf(var + 1e-5f));
  }
}

// ---- K2: fused LN + BOTH depthwise convs, register-blocked stencil ----
__global__ __launch_bounds__(256) void dw_both(const void* __restrict__ xsrc,
    size_t xoff, int fh, const int* __restrict__ flagp,
    const float2* __restrict__ stats,
    const float* __restrict__ g, const float* __restrict__ bt,
    const float* __restrict__ wx7,  const float* __restrict__ bx7,
    const float* __restrict__ wx11, const float* __restrict__ bx11,
    const float* __restrict__ wx21, const float* __restrict__ bx21,
    const float* __restrict__ wy7,  const float* __restrict__ by7,
    const float* __restrict__ wy11, const float* __restrict__ by11,
    const float* __restrict__ wy21, const float* __restrict__ by21,
    u16* __restrict__ sx, u16* __restrict__ sy)
{
  __shared__ float xnp[80][116];        // cols 0..15 & 96..111 zero halo
  __shared__ float cwx[21], cwy[21];
  __shared__ float cbs[2];
  int f = getf(fh, flagp);
  int bc = blockIdx.x;                  // bl*256 + c
  int c  = bc & 255;
  int bl = bc >> 8;
  int t = threadIdx.x;
  if (t < 21) {
    float v = wx21[c * 21 + t];
    if (t >= 5 && t <= 15) v += wx11[c * 11 + t - 5];
    if (t >= 7 && t <= 13) v += wx7[c * 7 + t - 7];
    cwx[t] = v;
  } else if (t < 42) {
    int j = t - 21;
    float v = wy21[c * 21 + j];
    if (j >= 5 && j <= 15) v += wy11[c * 11 + j - 5];
    if (j >= 7 && j <= 13) v += wy7[c * 7 + j - 7];
    cwy[j] = v;
  } else if (t == 42) { cbs[0] = bx7[c] + bx11[c] + bx21[c]; }
  else if (t == 43)   { cbs[1] = by7[c] + by11[c] + by21[c]; }
  // zero halo columns (80 rows x 32 cols)
  for (int i = t; i < 2560; i += 256) {
    int rr = i >> 5, cc = i & 31;
    xnp[rr][cc < 16 ? cc : 80 + cc] = 0.f;
  }
  float cg = g[c], cbt = bt[c];
  size_t xrow = xoff + (size_t)bc * NHW;
  const float2* st = stats + (size_t)bl * NHW;
  for (int i = t; i < NHW; i += 256) {
    float v = ldx(xsrc, xrow + i, f);
    float2 s = st[i];
    xnp[i / 80][16 + i % 80] = (v - s.x) * s.y * cg + cbt;
  }
  __syncthreads();
  float bxv = cbs[0], byv = cbs[1];
  size_t obase = (size_t)bc * NHW;
  for (int u = t; u < 800; u += 256) {  // 3 full rounds + 32-thread tail
    int h = u / 10, w0 = (u % 10) * 8;
    float r[32];
    #pragma unroll
    for (int j = 0; j < 8; j++)
      *(float4*)&r[4 * j] = *(const float4*)&xnp[h][w0 + 4 + 4 * j];
    float ax[8], ay[8];
    #pragma unroll
    for (int j = 0; j < 8; j++) { ax[j] = bxv; ay[j] = byv; }
    #pragma unroll
    for (int dd = 0; dd < 21; dd++) {
      float wv = cwx[dd];
      #pragma unroll
      for (int j = 0; j < 8; j++) ax[j] += wv * r[j + 2 + dd];
    }
    #pragma unroll
    for (int dd = 0; dd < 21; dd++) {
      int hp = h + dd - 10;
      int hc = min(max(hp, 0), 79);
      float wv = (hp == hc) ? cwy[dd] : 0.f;
      float4 v0 = *(const float4*)&xnp[hc][16 + w0];
      float4 v1 = *(const float4*)&xnp[hc][20 + w0];
      ay[0] += wv * v0.x; ay[1] += wv * v0.y; ay[2] += wv * v0.z; ay[3] += wv * v0.w;
      ay[4] += wv * v1.x; ay[5] += wv * v1.y; ay[6] += wv * v1.z; ay[7] += wv * v1.w;
    }
    size_t ob = obase + h * 80 + w0;
    ushort4 a0, a1, b0, b1;
    a0.x = f2b(ax[0]); a0.y = f2b(ax[1]); a0.z = f2b(ax[2]); a0.w = f2b(ax[3]);
    a1.x = f2b(ax[4]); a1.y = f2b(ax[5]); a1.z = f2b(ax[6]); a1.w = f2b(ax[7]);
    b0.x = f2b(ay[0]); b0.y = f2b(ay[1]); b0.z = f2b(ay[2]); b0.w = f2b(ay[3]);
    b1.x = f2b(ay[4]); b1.y = f2b(ay[5]); b1.z = f2b(ay[6]); b1.w = f2b(ay[7]);
    *(ushort4*)(sx + ob)     = a0;
    *(ushort4*)(sx + ob + 4) = a1;
    *(ushort4*)(sy + ob)     = b0;
    *(ushort4*)(sy + ob + 4) = b1;
  }
}

// ---- K3/K8: MFMA pointwise conv. C[o][p] = sum_k W[o][k]*In[k][p], W split
// into bf16 hi+lo. One block = full 256 o x 64 px strip of one batch.
// Round-7 changes (fixing round-6 spill regression: WRITE 240->568 MB was
// scratch traffic from 32 live prefetch VGPRs):
//  - NO W staging at all: A-fragments load DIRECTLY from the L2-resident
//    weight array (same 16B/lane the LDS round-trip reconstructed). Removes
//    all per-chunk barriers (loop is barrier-free after the InT stage) and
//    halves LDS to 32 KB for FINAL=0 (more blocks/CU for latency hiding).
//  - keeps the round-6 InT swizzle f(px) = (px ^ (px>>3)) & 7 (conflict fix).
// FINAL=1: out = acc + 2*bias + x, dtype-dispatched; else in-place bf16 + bias.
template<int FINAL>
__global__ __launch_bounds__(256) void pw_mfma_t(const u16* __restrict__ WB,
    u16* io0, u16* io1, const float* __restrict__ bias,
    void* __restrict__ OutBase, size_t out_off,
    const void* __restrict__ xsrc, size_t xoff,
    int fh, const int* __restrict__ flagp)
{
  __shared__ u16 S[FINAL ? 32768 : 16384];   // InT 32 KB; FINAL epilogue 64 KB
  u16* InT = S;
  int bl = blockIdx.y;
  int p0 = blockIdx.x * 64;
  int t  = threadIdx.x;
  int lane = t & 63, wid = t >> 6, lg = lane >> 4, lr = lane & 15;
  u16* io = (FINAL || blockIdx.z == 0) ? io0 : io1;

  // ---- stage InT with register 8x8 transpose; swizzled writes ----
  {
    int kb = t >> 3, pb = t & 7;
    const u16* src = io + (size_t)bl * NC * NHW + p0 + pb * 8;
    u32 r[8][4];
    #pragma unroll
    for (int i = 0; i < 8; i++) {
      uint4 v = *(const uint4*)(src + (size_t)(kb * 8 + i) * NHW);
      r[i][0] = v.x; r[i][1] = v.y; r[i][2] = v.z; r[i][3] = v.w;
    }
    #pragma unroll
    for (int j = 0; j < 8; j++) {
      u32 w[4];
      #pragma unroll
      for (int m = 0; m < 4; m++) {
        u32 a = r[2 * m][j >> 1], b = r[2 * m + 1][j >> 1];
        w[m] = (j & 1) ? ((a >> 16) | (b & 0xFFFF0000u))
                       : ((a & 0xFFFFu) | (b << 16));
      }
      int p = pb * 8 + j;
      *(uint4*)&InT[p * 256 + ((kb ^ ((j ^ pb) & 7)) * 8)] = make_uint4(w[0], w[1], w[2], w[3]);
    }
  }
  __syncthreads();

  f32x4 acc[4][4];
  #pragma unroll
  for (int m = 0; m < 4; m++)
    #pragma unroll
    for (int n = 0; n < 4; n++)
      acc[m][n] = (f32x4){0.f, 0.f, 0.f, 0.f};

  // A-frag base: row o = (wid*4+m)*16 + lr, k-offset lg*8 within chunk.
  const u16* wa = WB + ((wid * 4) * 16 + lr) * 256 + lg * 8;
  #pragma unroll 2
  for (int ch = 0; ch < 8; ch++) {
    bf16x8 bfr[4];
    #pragma unroll
    for (int n = 0; n < 4; n++) {
      int px = n * 16 + lr;
      int fpx = (px ^ (px >> 3)) & 7;
      bfr[n] = *(const bf16x8*)&InT[px * 256 + (((ch * 4 + lg) ^ fpx) * 8)];
    }
    #pragma unroll
    for (int m = 0; m < 4; m++) {
      const u16* wrow = wa + m * 16 * 256 + ch * 32;
      bf16x8 ahi = *(const bf16x8*)(wrow);
      bf16x8 alo = *(const bf16x8*)(wrow + 65536);
      #pragma unroll
      for (int n = 0; n < 4; n++) {
        acc[m][n] = __builtin_amdgcn_mfma_f32_16x16x32_bf16(ahi, bfr[n], acc[m][n], 0, 0, 0);
        acc[m][n] = __builtin_amdgcn_mfma_f32_16x16x32_bf16(alo, bfr[n], acc[m][n], 0, 0, 0);
      }
    }
  }
  __syncthreads();                       // all InT reads done before reuse

  // ---- epilogue via LDS round-trip for vectorized global stores ----
  if (FINAL) {
    float* Otf = (float*)S;             // [256 o][64 px] f32, swizzled
    #pragma unroll
    for (int m = 0; m < 4; m++)
      #pragma unroll
      for (int r = 0; r < 4; r++) {
        int o = (wid * 4 + m) * 16 + 4 * lg + r;
        float bv = 2.f * bias[o];
        #pragma unroll
        for (int n = 0; n < 4; n++) {
          int px = n * 16 + lr;
          Otf[o * 64 + (px ^ ((o & 7) * 8))] = acc[m][n][r] + bv;
        }
      }
    __syncthreads();
    int f = getf(fh, flagp);
    size_t gbase = ((size_t)bl * NC + t) * NHW + p0;
    #pragma unroll
    for (int j2 = 0; j2 < 16; j2++) {
      float4 v = *(float4*)&Otf[t * 64 + ((j2 * 4) ^ ((t & 7) * 8))];
      size_t gi = gbase + j2 * 4;
      if (f) {
        const float* xp = (const float*)xsrc + xoff + gi;
        v.x += xp[0]; v.y += xp[1]; v.z += xp[2]; v.w += xp[3];
        *(float4*)((float*)OutBase + out_off + gi) = v;
      } else {
        ushort4 xv = *(const ushort4*)((const u16*)xsrc + xoff + gi);
        ushort4 ov;
        ov.x = f2b(v.x + b2f(xv.x)); ov.y = f2b(v.y + b2f(xv.y));
        ov.z = f2b(v.z + b2f(xv.z)); ov.w = f2b(v.w + b2f(xv.w));
        *(ushort4*)((u16*)OutBase + out_off + gi) = ov;
      }
    }
  } else {
    u16* Ot = S;                        // [256 o][64 px] u16, swizzled
    #pragma unroll
    for (int m = 0; m < 4; m++)
      #pragma unroll
      for (int r = 0; r < 4; r++) {
        int o = (wid * 4 + m) * 16 + 4 * lg + r;
        float bv = bias[o];
        #pragma unroll
        for (int n = 0; n < 4; n++) {
          int px = n * 16 + lr;
          Ot[o * 64 + (px ^ ((o & 7) * 8))] = f2b(acc[m][n][r] + bv);
        }
      }
    __syncthreads();
    u16* orow = io + ((size_t)bl * NC + t) * NHW + p0;
    #pragma unroll
    for (int j = 0; j < 8; j++) {
      uint4 v = *(uint4*)&Ot[t * 64 + ((j ^ (t & 7)) * 8)];
      *(uint4*)(orow + j * 8) = v;
    }
  }
  (void)OutBase; (void)out_off; (void)xsrc; (void)xoff; (void)flagp; (void)io1;
}

// ---- K-T fused: per-plane 80x80 bf16 transpose + row/col sum of squares ----
__global__ __launch_bounds__(256) void transpose_sumsq(const u16* __restrict__ fx,
    const u16* __restrict__ fy, u16* __restrict__ fxT, u16* __restrict__ fyT,
    float* __restrict__ rs_fx, float* __restrict__ rs_fy,
    float* __restrict__ cs_fx, float* __restrict__ cs_fy)
{
  __shared__ u16 tile[80][81];
  int pl = blockIdx.x, ten = blockIdx.y;
  const u16* src = (ten ? fy : fx) + (size_t)pl * NHW;
  u16*       dst = (ten ? fyT : fxT) + (size_t)pl * NHW;
  int t = threadIdx.x;
  for (int i = t; i < NHW; i += 256) tile[i / 80][i % 80] = src[i];
  __syncthreads();
  for (int i = t; i < NHW; i += 256) dst[i] = tile[i % 80][i / 80];
  if (t < 80) {
    float s = 0.f;
    #pragma unroll
    for (int k = 0; k < 80; k++) { float v = b2f(tile[t][k]); s += v * v; }
    (ten ? rs_fy : rs_fx)[pl * 80 + t] = s;
  } else if (t < 160) {
    int w = t - 80; float s = 0.f;
    #pragma unroll
    for (int h = 0; h < 80; h++) { float v = b2f(tile[h][w]); s += v * v; }
    (ten ? cs_fy : cs_fx)[pl * 80 + w] = s;
  }
}

// ---- K5: combine over ci -> inverse norms ----
__global__ __launch_bounds__(256) void norm_combine(const float* __restrict__ rs_fx,
    const float* __restrict__ rs_fy, const float* __restrict__ cs_fx,
    const float* __restrict__ cs_fy, float* __restrict__ invn, int Nb)
{
  int t = blockIdx.x * 256 + threadIdx.x;   // 4*Nb*640 total
  int blk = Nb * 640;
  int side = t / blk, r = t % blk;
  int b = r / 640, rem = r % 640, hd = rem / 80, row = rem % 80;
  const float* src = (side == 0) ? rs_fy : (side == 1) ? rs_fx : (side == 2) ? cs_fx : cs_fy;
  size_t base = (size_t)(b * 256 + hd * 32) * 80 + row;
  float s = 0.f;
  #pragma unroll
  for (int ci = 0; ci < 32; ci++) s += src[base + ci * 80];
  invn[t] = 1.f / fmaxf(sqrtf(s), 1e-12f);
}

// ---- MFMA helpers for 80x80 Gram-style tiles ----
template<int T0, int NT>
__device__ __forceinline__ void gram_wave(const u16* pa, const u16* pb,
                                          int lg, int lr, f32x4* acc)
{
  constexpr int MLO = T0 / 5;
  #pragma unroll
  for (int ch = 0; ch < 3; ch++) {
    bool tz = (ch == 2) && (lg >= 2);
    int kk = ch * 32 + 8 * lg;
    if (tz) kk = 0;
    bf16x8 af[2], bf[5];
    #pragma unroll
    for (int m = 0; m < 2; m++)
      af[m] = *(const bf16x8*)(pa + ((MLO + m) * 16 + lr) * 80 + kk);
    #pragma unroll
    for (int n = 0; n < 5; n++)
      bf[n] = *(const bf16x8*)(pb + (n * 16 + lr) * 80 + kk);
    if (tz) {
      bf16x8 z = {0, 0, 0, 0, 0, 0, 0, 0};
      af[0] = z; af[1] = z;
    }
    #pragma unroll
    for (int j = 0; j < NT; j++) {
      acc[j] = __builtin_amdgcn_mfma_f32_16x16x32_bf16(
          af[(T0 + j) / 5 - MLO], bf[(T0 + j) % 5], acc[j], 0, 0, 0);
    }
  }
}

template<int T0, int NT>
__device__ __forceinline__ void gram_all(const u16* Ab, const u16* Bb,
                                         int lg, int lr, f32x4* acc)
{
  for (int ci = 0; ci < 32; ci++)
    gram_wave<T0, NT>(Ab + (size_t)ci * NHW, Bb + (size_t)ci * NHW, lg, lr, acc);
}

// ---- K6: MFMA Gram (sum over 32 ci) + cosine scale + softmax -> Sbuf ----
__global__ __launch_bounds__(256) void gram_softmax_mfma(const u16* __restrict__ fx,
    const u16* __restrict__ fy, const u16* __restrict__ fxT, const u16* __restrict__ fyT,
    const float* __restrict__ invn, u16* __restrict__ Sbuf, int Nb)
{
  __shared__ float At[80][81];
  int hd = blockIdx.x, b = blockIdx.y, axis = blockIdx.z;
  size_t sl0 = (size_t)(b * 256 + hd * 32) * NHW;
  const u16* Ab = (axis ? fxT : fy) + sl0;
  const u16* Bb = (axis ? fyT : fx) + sl0;
  int t = threadIdx.x, lane = t & 63, wid = t >> 6;
  int lg = lane >> 4, lr = lane & 15;
  f32x4 acc0 = {0.f, 0.f, 0.f, 0.f};
  f32x4 acc[7];
  #pragma unroll
  for (int j = 0; j < 7; j++) acc[j] = acc0;
  if      (wid == 0) gram_all<0, 7>(Ab, Bb, lg, lr, acc);
  else if (wid == 1) gram_all<7, 6>(Ab, Bb, lg, lr, acc);
  else if (wid == 2) gram_all<13, 6>(Ab, Bb, lg, lr, acc);
  else               gram_all<19, 6>(Ab, Bb, lg, lr, acc);
  int blk = Nb * 640;
  int rowbase = (b * 8 + hd) * 80;
  const float* invq = invn + (axis ? 2 * blk : 0)   + rowbase;
  const float* invk = invn + (axis ? 3 * blk : blk) + rowbase;
  int t0  = wid ? 6 * wid + 1 : 0;
  int cnt = wid ? 6 : 7;
  #pragma unroll
  for (int j = 0; j < 7; j++) {
    if (j < cnt) {
      int tt = t0 + j, m = tt / 5, n = tt % 5;
      int col = n * 16 + lr;
      float ik = invk[col];
      #pragma unroll
      for (int r = 0; r < 4; r++) {
        int row = m * 16 + 4 * lg + r;
        float gv = acc[j][r] * invq[row] * ik;
        At[row][col] = fminf(fmaxf(gv, -8.f), 8.f);  // |cos|<=1; NaN->-8
      }
    }
  }
  __syncthreads();
  u16* Sg = Sbuf + ((size_t)(axis * Nb * 8 + b * 8 + hd)) * NHW;
  if (t < 80) {
    float mx = -1e30f;
    for (int j = 0; j < 80; j++) mx = fmaxf(mx, At[t][j]);
    float s = 0.f;
    for (int j = 0; j < 80; j++) s += __expf(At[t][j] - mx);
    float inv = 1.f / s;
    for (int j = 0; j < 80; j++) Sg[t * 80 + j] = f2b(__expf(At[t][j] - mx) * inv);
  }
}

// ---- K7: MFMA fused H+W attention apply, IN PLACE over fx slice ----
template<int T0, int NT>
__device__ __forceinline__ void apply_wave(const u16* SH, const u16* fxT,
    const u16* fyP, const u16* SW, int lg, int lr, f32x4* acc)
{
  constexpr int MLO = T0 / 5;
  for (int ch = 0; ch < 3; ch++) {
    bool tz = (ch == 2) && (lg >= 2);
    int kk = ch * 32 + 8 * lg;
    if (tz) kk = 0;
    bf16x8 a1[2], a2[2], b1[5], b2[5];
    #pragma unroll
    for (int m = 0; m < 2; m++) {
      a1[m] = *(const bf16x8*)(SH  + ((MLO + m) * 16 + lr) * 80 + kk);
      a2[m] = *(const bf16x8*)(fyP + ((MLO + m) * 16 + lr) * 80 + kk);
    }
    #pragma unroll
    for (int n = 0; n < 5; n++) {
      b1[n] = *(const bf16x8*)(fxT + (n * 16 + lr) * 80 + kk);
      b2[n] = *(const bf16x8*)(SW  + (n * 16 + lr) * 80 + kk);
    }
    if (tz) {
      bf16x8 z = {0, 0, 0, 0, 0, 0, 0, 0};
      a1[0] = z; a1[1] = z; a2[0] = z; a2[1] = z;
    }
    #pragma unroll
    for (int j = 0; j < NT; j++) {
      acc[j] = __builtin_amdgcn_mfma_f32_16x16x32_bf16(
          a1[(T0 + j) / 5 - MLO], b1[(T0 + j) % 5], acc[j], 0, 0, 0);
      acc[j] = __builtin_amdgcn_mfma_f32_16x16x32_bf16(
          a2[(T0 + j) / 5 - MLO], b2[(T0 + j) % 5], acc[j], 0, 0, 0);
    }
  }
}

__global__ __launch_bounds__(256, 2) void apply_hw_mfma(const u16* __restrict__ fy_g,
    const u16* __restrict__ fxT_g, const u16* __restrict__ Sbuf,
    const float* __restrict__ invn, u16* fx_io, int Nb)
{
  int ci = blockIdx.x, hd = blockIdx.y, b = blockIdx.z;
  size_t off = (size_t)(b * 256 + hd * 32 + ci) * NHW;
  const u16* SgH = Sbuf + (size_t)(b * 8 + hd) * NHW;
  const u16* SgW = Sbuf + ((size_t)(Nb * 8) + b * 8 + hd) * NHW;
  const u16* fyP = fy_g + off;
  const u16* fxT = fxT_g + off;
  int t = threadIdx.x, lane = t & 63, wid = t >> 6;
  int lg = lane >> 4, lr = lane & 15;
  f32x4 acc0 = {0.f, 0.f, 0.f, 0.f};
  f32x4 acc[7];
  #pragma unroll
  for (int j = 0; j < 7; j++) acc[j] = acc0;
  if      (wid == 0) apply_wave<0, 7>(SgH, fxT, fyP, SgW, lg, lr, acc);
  else if (wid == 1) apply_wave<7, 6>(SgH, fxT, fyP, SgW, lg, lr, acc);
  else if (wid == 2) apply_wave<13, 6>(SgH, fxT, fyP, SgW, lg, lr, acc);
  else               apply_wave<19, 6>(SgH, fxT, fyP, SgW, lg, lr, acc);
  const float* invqH = invn + (b * 8 + hd) * 80;                 // H_fy(q)
  const float* invqW = invn + 2 * Nb * 640 + (b * 8 + hd) * 80;  // W_fx(q)
  int t0  = wid ? 6 * wid + 1 : 0;
  int cnt = wid ? 6 : 7;
  #pragma unroll
  for (int j = 0; j < 7; j++) {
    if (j < cnt) {
      int tt = t0 + j, m = tt / 5, n = tt % 5;
      int col = n * 16 + lr;
      float ivW = invqW[col];
      #pragma unroll
      for (int r = 0; r < 4; r++) {
        int row = m * 16 + 4 * lg + r;
        size_t ix = off + row * 80 + col;
        float v = acc[j][r] + b2f(fy_g[ix]) * invqH[row] + b2f(fx_io[ix]) * ivW;
        fx_io[ix] = f2b(v);
      }
    }
  }
}

extern "C" void kernel_launch(void* const* d_in, const int* in_sizes, int n_in,
                              void* d_out, int out_size, void* d_ws, size_t ws_size,
                              hipStream_t stream) {
  // Weight conversion table: d_in[1..18] in setup_inputs order.
  const int wsz[18] = {256, 256, 65536, 256, 65536, 256,
                       1792, 256, 2816, 256, 5376, 256,
                       1792, 256, 2816, 256, 5376, 256};
  CvtArgs ca;
  int cum = 0;
  for (int i = 0; i < 18; i++) { ca.src[i] = d_in[i + 1]; ca.cum[i] = cum; cum += wsz[i]; }
  ca.cum[18] = cum;   // 153600

  // Host-side dtype detection: x (and out) have 26,214,400 elements, so
  // 104857600 bytes => f32, 52428800 => bf16. Try in_sizes[0] AND out_size.
  // Fall back to the fast device probe only if neither matches.
  int hostf = -1;
  if (in_sizes && n_in > 0) {
    if      (in_sizes[0] == 104857600) hostf = 1;
    else if (in_sizes[0] == 52428800)  hostf = 0;
  }
  if (hostf < 0) {
    if      (out_size == 104857600) hostf = 1;
    else if (out_size == 52428800)  hostf = 0;
  }

  // ws layout: flag(16) | wbuf(614400) | wsplit(524288) | per-chunk buffers.
  int Nb = 1;
  for (int cand = 16; cand >= 1; cand >>= 1) {
    size_t need = (size_t)cand * 13701120 + 614416 + 524288;
    if (need <= ws_size) { Nb = cand; break; }
  }
  char* p = (char*)d_ws;
  int*    flag  = (int*)p;    p += 16;
  float*  wbuf  = (float*)p;  p += 614400;
  u16*    wsplit= (u16*)p;    p += 524288;     // [2 mat][2 set][256][256] bf16
  u16*    fxbuf = (u16*)p;    p += (size_t)Nb * 3276800;
  u16*    fybuf = (u16*)p;    p += (size_t)Nb * 3276800;
  u16*    fxT   = (u16*)p;    p += (size_t)Nb * 3276800;
  u16*    fyT   = (u16*)p;    p += (size_t)Nb * 3276800;
  float2* stats = (float2*)p; p += (size_t)Nb * 51200;
  float*  rs_fx = (float*)p;  p += (size_t)Nb * 81920;
  float*  rs_fy = (float*)p;  p += (size_t)Nb * 81920;
  float*  cs_fx = (float*)p;  p += (size_t)Nb * 81920;
  float*  cs_fy = (float*)p;  p += (size_t)Nb * 81920;
  float*  invn  = (float*)p;  p += (size_t)Nb * 10240;
  u16*    Sbuf  = (u16*)p;

  // f32 weight views
  float* ln_g = wbuf + ca.cum[0];  float* ln_b = wbuf + ca.cum[1];
  float* w_in = wbuf + ca.cum[2];  float* b_in = wbuf + ca.cum[3];
  float* w_out= wbuf + ca.cum[4]; float* b_out= wbuf + ca.cum[5];
  float* wx7  = wbuf + ca.cum[6];  float* bx7  = wbuf + ca.cum[7];
  float* wx11 = wbuf + ca.cum[8];  float* bx11 = wbuf + ca.cum[9];
  float* wx21 = wbuf + ca.cum[10]; float* bx21 = wbuf + ca.cum[11];
  float* wy7  = wbuf + ca.cum[12]; float* by7  = wbuf + ca.cum[13];
  float* wy11 = wbuf + ca.cum[14]; float* by11 = wbuf + ca.cum[15];
  float* wy21 = wbuf + ca.cum[16]; float* by21 = wbuf + ca.cum[17];

  if (hostf < 0) {
    probe_init<<<dim3(1), dim3(1), 0, stream>>>(flag);
    probe_count<<<dim3(64), dim3(256), 0, stream>>>((const u16*)d_in[0], flag);
    probe_decide<<<dim3(1), dim3(1), 0, stream>>>(flag);
  }
  cvt_weights<<<dim3(600), dim3(256), 0, stream>>>(ca, wbuf, hostf, flag);
  split_w<<<dim3(512), dim3(256), 0, stream>>>(w_in, w_out, wsplit);

  for (int b0 = 0; b0 < NB; b0 += Nb) {
    size_t xoff = (size_t)b0 * NC * NHW;   // element offset of chunk in x / out

    ln_stats<<<dim3(7, Nb), dim3(256), 0, stream>>>(d_in[0], xoff, hostf, flag, stats);
    dw_both<<<dim3(Nb * 256), dim3(256), 0, stream>>>(d_in[0], xoff, hostf, flag, stats,
        ln_g, ln_b, wx7, bx7, wx11, bx11, wx21, bx21,
        wy7, by7, wy11, by11, wy21, by21, fxbuf, fybuf);
    pw_mfma_t<0><<<dim3(100, Nb, 2), dim3(256), 0, stream>>>(wsplit, fxbuf, fybuf,
        b_in, nullptr, 0, nullptr, 0, hostf, flag);
    transpose_sumsq<<<dim3(Nb * 256, 2), dim3(256), 0, stream>>>(fxbuf, fybuf, fxT, fyT,
        rs_fx, rs_fy, cs_fx, cs_fy);
    norm_combine<<<dim3(10 * Nb), dim3(256), 0, stream>>>(rs_fx, rs_fy, cs_fx, cs_fy, invn, Nb);
    gram_softmax_mfma<<<dim3(8, Nb, 2), dim3(256), 0, stream>>>(fxbuf, fybuf, fxT, fyT, invn, Sbuf, Nb);
    apply_hw_mfma<<<dim3(32, 8, Nb), dim3(256), 0, stream>>>(fybuf, fxT, Sbuf, invn, fxbuf, Nb);
    pw_mfma_t<1><<<dim3(100, Nb, 1), dim3(256), 0, stream>>>(wsplit + 131072, fxbuf, nullptr,
        b_out, d_out, xoff, d_in[0], xoff, hostf, flag);
  }
  (void)in_sizes; (void)n_in; (void)out_size;
}

// Round 8
// 884.220 us; speedup vs baseline: 1.2171x; 1.0045x over previous
//
#include <hip/hip_runtime.h>

typedef unsigned short u16;
typedef unsigned int   u32;

#define NB  16
#define NC  256
#define NH  80
#define NW  80
#define NHW 6400

typedef short bf16x8 __attribute__((ext_vector_type(8)));
typedef float f32x4  __attribute__((ext_vector_type(4)));

__device__ __forceinline__ float b2f(u16 u) {
  union { u32 i; float f; } c; c.i = ((u32)u) << 16; return c.f;
}
__device__ __forceinline__ u16 f2b(float f) {
  union { float f; u32 i; } c; c.f = f;
  return (u16)((c.i + 0x7FFFu + ((c.i >> 16) & 1u)) >> 16);
}
// dtype-dispatched input load (flag=1: f32, flag=0: bf16)
__device__ __forceinline__ float ldx(const void* p, size_t i, int f32f) {
  return f32f ? ((const float*)p)[i] : b2f(((const u16*)p)[i]);
}
// resolve dtype flag: host-decided (fh>=0) or device-probed fallback
__device__ __forceinline__ int getf(int fh, const int* flagp) {
  return (fh >= 0) ? fh : *flagp;
}

// ---- K0a (fallback only): fast parallel dtype probe ----
__global__ void probe_init(int* __restrict__ flag) { flag[0] = 0; flag[1] = 0; }

__global__ __launch_bounds__(256) void probe_count(const u16* __restrict__ x,
                                                   int* __restrict__ flag)
{
  __shared__ int cnt[256];
  int base = (blockIdx.x * 256 + threadIdx.x) * 16;   // 64*256*16 = 262144
  int c = 0;
  uint4 v0 = *(const uint4*)(x + base);
  uint4 v1 = *(const uint4*)(x + base + 8);
  u32 w[8] = {v0.x, v0.y, v0.z, v0.w, v1.x, v1.y, v1.z, v1.w};
  #pragma unroll
  for (int j = 0; j < 8; j++) {
    if (((w[j] >> 7)  & 0xFFu) == 0xFFu) c++;
    if (((w[j] >> 23) & 0xFFu) == 0xFFu) c++;
  }
  cnt[threadIdx.x] = c; __syncthreads();
  for (int s = 128; s > 0; s >>= 1) {
    if (threadIdx.x < s) cnt[threadIdx.x] += cnt[threadIdx.x + s];
    __syncthreads();
  }
  if (threadIdx.x == 0) atomicAdd(&flag[1], cnt[0]);
}

__global__ void probe_decide(int* __restrict__ flag) {
  flag[0] = (flag[1] > 16) ? 1 : 0;
}

// ---- K0b: convert all 18 weight/bias arrays into one f32 table ----
struct CvtArgs { const void* src[18]; int cum[19]; };

__global__ __launch_bounds__(256) void cvt_weights(CvtArgs a, float* __restrict__ dst,
                                                   int fh, const int* __restrict__ flagp)
{
  int f = getf(fh, flagp);
  int i = blockIdx.x * 256 + threadIdx.x;     // < 153600
  int s = 0;
  while (i >= a.cum[s + 1]) s++;
  int j = i - a.cum[s];
  float v = f ? ((const float*)a.src[s])[j] : b2f(((const u16*)a.src[s])[j]);
  if (!(v == v) || fabsf(v) > 1e30f) v = 0.f;  // scrub
  dst[i] = v;
}

// ---- K0c: split w_in / w_out into bf16 hi+lo pairs for MFMA.
// WB layout: [mat][set][256 o][256 k] u16, mat stride 131072, set stride 65536.
__global__ __launch_bounds__(256) void split_w(const float* __restrict__ w_in,
    const float* __restrict__ w_out, u16* __restrict__ WB)
{
  int i = blockIdx.x * 256 + threadIdx.x;   // < 131072
  int mat = i >> 16, idx = i & 65535;
  float v = (mat ? w_out : w_in)[idx];
  u16 hi = f2b(v);
  u16 lo = f2b(v - b2f(hi));
  WB[mat * 131072 + idx] = hi;
  WB[mat * 131072 + 65536 + idx] = lo;
}

// ---- K1: per-pixel LN stats (mean, rstd) over C; 4 px/thread vectorized ----
__global__ __launch_bounds__(256) void ln_stats(const void* __restrict__ xsrc,
    size_t xoff, int fh, const int* __restrict__ flagp, float2* __restrict__ stats)
{
  int f = getf(fh, flagp);
  int bl = blockIdx.y;
  int p4 = blockIdx.x * 1024 + threadIdx.x * 4;
  if (p4 >= NHW) return;                       // last block covers 256 px only
  size_t base = xoff + (size_t)bl * NC * NHW + p4;
  float s1[4] = {0.f, 0.f, 0.f, 0.f}, s2[4] = {0.f, 0.f, 0.f, 0.f};
  if (f) {
    const float* xp = (const float*)xsrc + base;
    for (int c = 0; c < NC; c++) {
      float4 v = *(const float4*)(xp + (size_t)c * NHW);
      s1[0] += v.x; s2[0] += v.x * v.x;
      s1[1] += v.y; s2[1] += v.y * v.y;
      s1[2] += v.z; s2[2] += v.z * v.z;
      s1[3] += v.w; s2[3] += v.w * v.w;
    }
  } else {
    const u16* xp = (const u16*)xsrc + base;
    for (int c = 0; c < NC; c++) {
      ushort4 v = *(const ushort4*)(xp + (size_t)c * NHW);
      float a = b2f(v.x), b = b2f(v.y), cc = b2f(v.z), d = b2f(v.w);
      s1[0] += a;  s2[0] += a * a;
      s1[1] += b;  s2[1] += b * b;
      s1[2] += cc; s2[2] += cc * cc;
      s1[3] += d;  s2[3] += d * d;
    }
  }
  float2* so = stats + (size_t)bl * NHW + p4;
  #pragma unroll
  for (int j = 0; j < 4; j++) {
    float mean = s1[j] * (1.f / 256.f);
    float var  = s2[j] * (1.f / 256.f) - mean * mean;
    so[j] = make_float2(mean, rsqrtf(var + 1e-5f));
  }
}

// ---- K2: fused LN + BOTH depthwise convs, register-blocked stencil ----
__global__ __launch_bounds__(256) void dw_both(const void* __restrict__ xsrc,
    size_t xoff, int fh, const int* __restrict__ flagp,
    const float2* __restrict__ stats,
    const float* __restrict__ g, const float* __restrict__ bt,
    const float* __restrict__ wx7,  const float* __restrict__ bx7,
    const float* __restrict__ wx11, const float* __restrict__ bx11,
    const float* __restrict__ wx21, const float* __restrict__ bx21,
    const float* __restrict__ wy7,  const float* __restrict__ by7,
    const float* __restrict__ wy11, const float* __restrict__ by11,
    const float* __restrict__ wy21, const float* __restrict__ by21,
    u16* __restrict__ sx, u16* __restrict__ sy)
{
  __shared__ float xnp[80][116];        // cols 0..15 & 96..111 zero halo
  __shared__ float cwx[21], cwy[21];
  __shared__ float cbs[2];
  int f = getf(fh, flagp);
  int bc = blockIdx.x;                  // bl*256 + c
  int c  = bc & 255;
  int bl = bc >> 8;
  int t = threadIdx.x;
  if (t < 21) {
    float v = wx21[c * 21 + t];
    if (t >= 5 && t <= 15) v += wx11[c * 11 + t - 5];
    if (t >= 7 && t <= 13) v += wx7[c * 7 + t - 7];
    cwx[t] = v;
  } else if (t < 42) {
    int j = t - 21;
    float v = wy21[c * 21 + j];
    if (j >= 5 && j <= 15) v += wy11[c * 11 + j - 5];
    if (j >= 7 && j <= 13) v += wy7[c * 7 + j - 7];
    cwy[j] = v;
  } else if (t == 42) { cbs[0] = bx7[c] + bx11[c] + bx21[c]; }
  else if (t == 43)   { cbs[1] = by7[c] + by11[c] + by21[c]; }
  // zero halo columns (80 rows x 32 cols)
  for (int i = t; i < 2560; i += 256) {
    int rr = i >> 5, cc = i & 31;
    xnp[rr][cc < 16 ? cc : 80 + cc] = 0.f;
  }
  float cg = g[c], cbt = bt[c];
  size_t xrow = xoff + (size_t)bc * NHW;
  const float2* st = stats + (size_t)bl * NHW;
  for (int i = t; i < NHW; i += 256) {
    float v = ldx(xsrc, xrow + i, f);
    float2 s = st[i];
    xnp[i / 80][16 + i % 80] = (v - s.x) * s.y * cg + cbt;
  }
  __syncthreads();
  float bxv = cbs[0], byv = cbs[1];
  size_t obase = (size_t)bc * NHW;
  for (int u = t; u < 800; u += 256) {  // 3 full rounds + 32-thread tail
    int h = u / 10, w0 = (u % 10) * 8;
    float r[32];
    #pragma unroll
    for (int j = 0; j < 8; j++)
      *(float4*)&r[4 * j] = *(const float4*)&xnp[h][w0 + 4 + 4 * j];
    float ax[8], ay[8];
    #pragma unroll
    for (int j = 0; j < 8; j++) { ax[j] = bxv; ay[j] = byv; }
    #pragma unroll
    for (int dd = 0; dd < 21; dd++) {
      float wv = cwx[dd];
      #pragma unroll
      for (int j = 0; j < 8; j++) ax[j] += wv * r[j + 2 + dd];
    }
    #pragma unroll
    for (int dd = 0; dd < 21; dd++) {
      int hp = h + dd - 10;
      int hc = min(max(hp, 0), 79);
      float wv = (hp == hc) ? cwy[dd] : 0.f;
      float4 v0 = *(const float4*)&xnp[hc][16 + w0];
      float4 v1 = *(const float4*)&xnp[hc][20 + w0];
      ay[0] += wv * v0.x; ay[1] += wv * v0.y; ay[2] += wv * v0.z; ay[3] += wv * v0.w;
      ay[4] += wv * v1.x; ay[5] += wv * v1.y; ay[6] += wv * v1.z; ay[7] += wv * v1.w;
    }
    size_t ob = obase + h * 80 + w0;
    ushort4 a0, a1, b0, b1;
    a0.x = f2b(ax[0]); a0.y = f2b(ax[1]); a0.z = f2b(ax[2]); a0.w = f2b(ax[3]);
    a1.x = f2b(ax[4]); a1.y = f2b(ax[5]); a1.z = f2b(ax[6]); a1.w = f2b(ax[7]);
    b0.x = f2b(ay[0]); b0.y = f2b(ay[1]); b0.z = f2b(ay[2]); b0.w = f2b(ay[3]);
    b1.x = f2b(ay[4]); b1.y = f2b(ay[5]); b1.z = f2b(ay[6]); b1.w = f2b(ay[7]);
    *(ushort4*)(sx + ob)     = a0;
    *(ushort4*)(sx + ob + 4) = a1;
    *(ushort4*)(sy + ob)     = b0;
    *(ushort4*)(sy + ob + 4) = b1;
  }
}

// ---- K3/K8: MFMA pointwise conv. C[o][p] = sum_k W[o][k]*In[k][p], W split
// into bf16 hi+lo. One block = full 256 o x 64 px strip of one batch.
// Round-8: FINAL epilogue processes o in two halves of 128 through a 32 KB
// LDS tile (was 64 KB) -> 5 blocks/CU instead of 2 (occupancy was the cap:
// 17.6% measured, MfmaUtil 5.7%, L2 W-load latency un-hidden).
// A-fragments load DIRECTLY from the L2-resident weight array; InT swizzle
// f(px) = (px ^ (px>>3)) & 7 on both write and read.
// FINAL=1: out = acc + 2*bias + x, dtype-dispatched; else in-place bf16 + bias.
template<int FINAL>
__global__ __launch_bounds__(256) void pw_mfma_t(const u16* __restrict__ WB,
    u16* io0, u16* io1, const float* __restrict__ bias,
    void* __restrict__ OutBase, size_t out_off,
    const void* __restrict__ xsrc, size_t xoff,
    int fh, const int* __restrict__ flagp)
{
  __shared__ u16 S[16384];              // 32 KB for BOTH variants
  u16* InT = S;
  int bl = blockIdx.y;
  int p0 = blockIdx.x * 64;
  int t  = threadIdx.x;
  int lane = t & 63, wid = t >> 6, lg = lane >> 4, lr = lane & 15;
  u16* io = (FINAL || blockIdx.z == 0) ? io0 : io1;

  // ---- stage InT with register 8x8 transpose; swizzled writes ----
  {
    int kb = t >> 3, pb = t & 7;
    const u16* src = io + (size_t)bl * NC * NHW + p0 + pb * 8;
    u32 r[8][4];
    #pragma unroll
    for (int i = 0; i < 8; i++) {
      uint4 v = *(const uint4*)(src + (size_t)(kb * 8 + i) * NHW);
      r[i][0] = v.x; r[i][1] = v.y; r[i][2] = v.z; r[i][3] = v.w;
    }
    #pragma unroll
    for (int j = 0; j < 8; j++) {
      u32 w[4];
      #pragma unroll
      for (int m = 0; m < 4; m++) {
        u32 a = r[2 * m][j >> 1], b = r[2 * m + 1][j >> 1];
        w[m] = (j & 1) ? ((a >> 16) | (b & 0xFFFF0000u))
                       : ((a & 0xFFFFu) | (b << 16));
      }
      int p = pb * 8 + j;
      *(uint4*)&InT[p * 256 + ((kb ^ ((j ^ pb) & 7)) * 8)] = make_uint4(w[0], w[1], w[2], w[3]);
    }
  }
  __syncthreads();

  f32x4 acc[4][4];
  #pragma unroll
  for (int m = 0; m < 4; m++)
    #pragma unroll
    for (int n = 0; n < 4; n++)
      acc[m][n] = (f32x4){0.f, 0.f, 0.f, 0.f};

  // A-frag base: row o = (wid*4+m)*16 + lr, k-offset lg*8 within chunk.
  const u16* wa = WB + ((wid * 4) * 16 + lr) * 256 + lg * 8;
  #pragma unroll 2
  for (int ch = 0; ch < 8; ch++) {
    bf16x8 bfr[4];
    #pragma unroll
    for (int n = 0; n < 4; n++) {
      int px = n * 16 + lr;
      int fpx = (px ^ (px >> 3)) & 7;
      bfr[n] = *(const bf16x8*)&InT[px * 256 + (((ch * 4 + lg) ^ fpx) * 8)];
    }
    #pragma unroll
    for (int m = 0; m < 4; m++) {
      const u16* wrow = wa + m * 16 * 256 + ch * 32;
      bf16x8 ahi = *(const bf16x8*)(wrow);
      bf16x8 alo = *(const bf16x8*)(wrow + 65536);
      #pragma unroll
      for (int n = 0; n < 4; n++) {
        acc[m][n] = __builtin_amdgcn_mfma_f32_16x16x32_bf16(ahi, bfr[n], acc[m][n], 0, 0, 0);
        acc[m][n] = __builtin_amdgcn_mfma_f32_16x16x32_bf16(alo, bfr[n], acc[m][n], 0, 0, 0);
      }
    }
  }
  __syncthreads();                       // all InT reads done before reuse

  // ---- epilogue via LDS round-trip for vectorized global stores ----
  if (FINAL) {
    float* Otf = (float*)S;             // [128 o][64 px] f32 = 32 KB, swizzled
    int f = getf(fh, flagp);
    #pragma unroll
    for (int h = 0; h < 2; h++) {
      if ((wid >> 1) == h) {            // waves owning this o-half write LDS
        #pragma unroll
        for (int m = 0; m < 4; m++)
          #pragma unroll
          for (int r = 0; r < 4; r++) {
            int o  = (wid * 4 + m) * 16 + 4 * lg + r;
            int ol = o & 127;
            float bv = 2.f * bias[o];
            #pragma unroll
            for (int n = 0; n < 4; n++) {
              int px = n * 16 + lr;
              Otf[ol * 64 + (px ^ ((ol & 7) * 8))] = acc[m][n][r] + bv;
            }
          }
      }
      __syncthreads();
      // all 256 threads store: row rl = t>>1, 32-f32 segment (t&1)
      int rl = t >> 1, seg = (t & 1) * 32;
      int o = h * 128 + rl;
      size_t gbase = ((size_t)bl * NC + o) * NHW + p0 + seg;
      #pragma unroll
      for (int j2 = 0; j2 < 8; j2++) {
        int cj = (seg + 4 * j2) ^ ((rl & 7) * 8);
        float4 v = *(float4*)&Otf[rl * 64 + cj];
        size_t gi = gbase + j2 * 4;
        if (f) {
          const float* xp = (const float*)xsrc + xoff + gi;
          v.x += xp[0]; v.y += xp[1]; v.z += xp[2]; v.w += xp[3];
          *(float4*)((float*)OutBase + out_off + gi) = v;
        } else {
          ushort4 xv = *(const ushort4*)((const u16*)xsrc + xoff + gi);
          ushort4 ov;
          ov.x = f2b(v.x + b2f(xv.x)); ov.y = f2b(v.y + b2f(xv.y));
          ov.z = f2b(v.z + b2f(xv.z)); ov.w = f2b(v.w + b2f(xv.w));
          *(ushort4*)((u16*)OutBase + out_off + gi) = ov;
        }
      }
      __syncthreads();                  // Otf free for next half
    }
  } else {
    u16* Ot = S;                        // [256 o][64 px] u16 = 32 KB, swizzled
    #pragma unroll
    for (int m = 0; m < 4; m++)
      #pragma unroll
      for (int r = 0; r < 4; r++) {
        int o = (wid * 4 + m) * 16 + 4 * lg + r;
        float bv = bias[o];
        #pragma unroll
        for (int n = 0; n < 4; n++) {
          int px = n * 16 + lr;
          Ot[o * 64 + (px ^ ((o & 7) * 8))] = f2b(acc[m][n][r] + bv);
        }
      }
    __syncthreads();
    u16* orow = io + ((size_t)bl * NC + t) * NHW + p0;
    #pragma unroll
    for (int j = 0; j < 8; j++) {
      uint4 v = *(uint4*)&Ot[t * 64 + ((j ^ (t & 7)) * 8)];
      *(uint4*)(orow + j * 8) = v;
    }
  }
  (void)OutBase; (void)out_off; (void)xsrc; (void)xoff; (void)flagp; (void)io1;
}

// ---- K-T fused: per-plane 80x80 bf16 transpose + row/col sum of squares ----
__global__ __launch_bounds__(256) void transpose_sumsq(const u16* __restrict__ fx,
    const u16* __restrict__ fy, u16* __restrict__ fxT, u16* __restrict__ fyT,
    float* __restrict__ rs_fx, float* __restrict__ rs_fy,
    float* __restrict__ cs_fx, float* __restrict__ cs_fy)
{
  __shared__ u16 tile[80][81];
  int pl = blockIdx.x, ten = blockIdx.y;
  const u16* src = (ten ? fy : fx) + (size_t)pl * NHW;
  u16*       dst = (ten ? fyT : fxT) + (size_t)pl * NHW;
  int t = threadIdx.x;
  for (int i = t; i < NHW; i += 256) tile[i / 80][i % 80] = src[i];
  __syncthreads();
  for (int i = t; i < NHW; i += 256) dst[i] = tile[i % 80][i / 80];
  if (t < 80) {
    float s = 0.f;
    #pragma unroll
    for (int k = 0; k < 80; k++) { float v = b2f(tile[t][k]); s += v * v; }
    (ten ? rs_fy : rs_fx)[pl * 80 + t] = s;
  } else if (t < 160) {
    int w = t - 80; float s = 0.f;
    #pragma unroll
    for (int h = 0; h < 80; h++) { float v = b2f(tile[h][w]); s += v * v; }
    (ten ? cs_fy : cs_fx)[pl * 80 + w] = s;
  }
}

// ---- K5: combine over ci -> inverse norms ----
__global__ __launch_bounds__(256) void norm_combine(const float* __restrict__ rs_fx,
    const float* __restrict__ rs_fy, const float* __restrict__ cs_fx,
    const float* __restrict__ cs_fy, float* __restrict__ invn, int Nb)
{
  int t = blockIdx.x * 256 + threadIdx.x;   // 4*Nb*640 total
  int blk = Nb * 640;
  int side = t / blk, r = t % blk;
  int b = r / 640, rem = r % 640, hd = rem / 80, row = rem % 80;
  const float* src = (side == 0) ? rs_fy : (side == 1) ? rs_fx : (side == 2) ? cs_fx : cs_fy;
  size_t base = (size_t)(b * 256 + hd * 32) * 80 + row;
  float s = 0.f;
  #pragma unroll
  for (int ci = 0; ci < 32; ci++) s += src[base + ci * 80];
  invn[t] = 1.f / fmaxf(sqrtf(s), 1e-12f);
}

// ---- MFMA helpers for 80x80 Gram-style tiles ----
template<int T0, int NT>
__device__ __forceinline__ void gram_wave(const u16* pa, const u16* pb,
                                          int lg, int lr, f32x4* acc)
{
  constexpr int MLO = T0 / 5;
  #pragma unroll
  for (int ch = 0; ch < 3; ch++) {
    bool tz = (ch == 2) && (lg >= 2);
    int kk = ch * 32 + 8 * lg;
    if (tz) kk = 0;
    bf16x8 af[2], bf[5];
    #pragma unroll
    for (int m = 0; m < 2; m++)
      af[m] = *(const bf16x8*)(pa + ((MLO + m) * 16 + lr) * 80 + kk);
    #pragma unroll
    for (int n = 0; n < 5; n++)
      bf[n] = *(const bf16x8*)(pb + (n * 16 + lr) * 80 + kk);
    if (tz) {
      bf16x8 z = {0, 0, 0, 0, 0, 0, 0, 0};
      af[0] = z; af[1] = z;
    }
    #pragma unroll
    for (int j = 0; j < NT; j++) {
      acc[j] = __builtin_amdgcn_mfma_f32_16x16x32_bf16(
          af[(T0 + j) / 5 - MLO], bf[(T0 + j) % 5], acc[j], 0, 0, 0);
    }
  }
}

template<int T0, int NT>
__device__ __forceinline__ void gram_all(const u16* Ab, const u16* Bb,
                                         int lg, int lr, f32x4* acc)
{
  for (int ci = 0; ci < 32; ci++)
    gram_wave<T0, NT>(Ab + (size_t)ci * NHW, Bb + (size_t)ci * NHW, lg, lr, acc);
}

// ---- K6: MFMA Gram (sum over 32 ci) + cosine scale + softmax -> Sbuf ----
__global__ __launch_bounds__(256) void gram_softmax_mfma(const u16* __restrict__ fx,
    const u16* __restrict__ fy, const u16* __restrict__ fxT, const u16* __restrict__ fyT,
    const float* __restrict__ invn, u16* __restrict__ Sbuf, int Nb)
{
  __shared__ float At[80][81];
  int hd = blockIdx.x, b = blockIdx.y, axis = blockIdx.z;
  size_t sl0 = (size_t)(b * 256 + hd * 32) * NHW;
  const u16* Ab = (axis ? fxT : fy) + sl0;
  const u16* Bb = (axis ? fyT : fx) + sl0;
  int t = threadIdx.x, lane = t & 63, wid = t >> 6;
  int lg = lane >> 4, lr = lane & 15;
  f32x4 acc0 = {0.f, 0.f, 0.f, 0.f};
  f32x4 acc[7];
  #pragma unroll
  for (int j = 0; j < 7; j++) acc[j] = acc0;
  if      (wid == 0) gram_all<0, 7>(Ab, Bb, lg, lr, acc);
  else if (wid == 1) gram_all<7, 6>(Ab, Bb, lg, lr, acc);
  else if (wid == 2) gram_all<13, 6>(Ab, Bb, lg, lr, acc);
  else               gram_all<19, 6>(Ab, Bb, lg, lr, acc);
  int blk = Nb * 640;
  int rowbase = (b * 8 + hd) * 80;
  const float* invq = invn + (axis ? 2 * blk : 0)   + rowbase;
  const float* invk = invn + (axis ? 3 * blk : blk) + rowbase;
  int t0  = wid ? 6 * wid + 1 : 0;
  int cnt = wid ? 6 : 7;
  #pragma unroll
  for (int j = 0; j < 7; j++) {
    if (j < cnt) {
      int tt = t0 + j, m = tt / 5, n = tt % 5;
      int col = n * 16 + lr;
      float ik = invk[col];
      #pragma unroll
      for (int r = 0; r < 4; r++) {
        int row = m * 16 + 4 * lg + r;
        float gv = acc[j][r] * invq[row] * ik;
        At[row][col] = fminf(fmaxf(gv, -8.f), 8.f);  // |cos|<=1; NaN->-8
      }
    }
  }
  __syncthreads();
  u16* Sg = Sbuf + ((size_t)(axis * Nb * 8 + b * 8 + hd)) * NHW;
  if (t < 80) {
    float mx = -1e30f;
    for (int j = 0; j < 80; j++) mx = fmaxf(mx, At[t][j]);
    float s = 0.f;
    for (int j = 0; j < 80; j++) s += __expf(At[t][j] - mx);
    float inv = 1.f / s;
    for (int j = 0; j < 80; j++) Sg[t * 80 + j] = f2b(__expf(At[t][j] - mx) * inv);
  }
}

// ---- K7: MFMA fused H+W attention apply, IN PLACE over fx slice ----
template<int T0, int NT>
__device__ __forceinline__ void apply_wave(const u16* SH, const u16* fxT,
    const u16* fyP, const u16* SW, int lg, int lr, f32x4* acc)
{
  constexpr int MLO = T0 / 5;
  for (int ch = 0; ch < 3; ch++) {
    bool tz = (ch == 2) && (lg >= 2);
    int kk = ch * 32 + 8 * lg;
    if (tz) kk = 0;
    bf16x8 a1[2], a2[2], b1[5], b2[5];
    #pragma unroll
    for (int m = 0; m < 2; m++) {
      a1[m] = *(const bf16x8*)(SH  + ((MLO + m) * 16 + lr) * 80 + kk);
      a2[m] = *(const bf16x8*)(fyP + ((MLO + m) * 16 + lr) * 80 + kk);
    }
    #pragma unroll
    for (int n = 0; n < 5; n++) {
      b1[n] = *(const bf16x8*)(fxT + (n * 16 + lr) * 80 + kk);
      b2[n] = *(const bf16x8*)(SW  + (n * 16 + lr) * 80 + kk);
    }
    if (tz) {
      bf16x8 z = {0, 0, 0, 0, 0, 0, 0, 0};
      a1[0] = z; a1[1] = z; a2[0] = z; a2[1] = z;
    }
    #pragma unroll
    for (int j = 0; j < NT; j++) {
      acc[j] = __builtin_amdgcn_mfma_f32_16x16x32_bf16(
          a1[(T0 + j) / 5 - MLO], b1[(T0 + j) % 5], acc[j], 0, 0, 0);
      acc[j] = __builtin_amdgcn_mfma_f32_16x16x32_bf16(
          a2[(T0 + j) / 5 - MLO], b2[(T0 + j) % 5], acc[j], 0, 0, 0);
    }
  }
}

__global__ __launch_bounds__(256, 2) void apply_hw_mfma(const u16* __restrict__ fy_g,
    const u16* __restrict__ fxT_g, const u16* __restrict__ Sbuf,
    const float* __restrict__ invn, u16* fx_io, int Nb)
{
  int ci = blockIdx.x, hd = blockIdx.y, b = blockIdx.z;
  size_t off = (size_t)(b * 256 + hd * 32 + ci) * NHW;
  const u16* SgH = Sbuf + (size_t)(b * 8 + hd) * NHW;
  const u16* SgW = Sbuf + ((size_t)(Nb * 8) + b * 8 + hd) * NHW;
  const u16* fyP = fy_g + off;
  const u16* fxT = fxT_g + off;
  int t = threadIdx.x, lane = t & 63, wid = t >> 6;
  int lg = lane >> 4, lr = lane & 15;
  f32x4 acc0 = {0.f, 0.f, 0.f, 0.f};
  f32x4 acc[7];
  #pragma unroll
  for (int j = 0; j < 7; j++) acc[j] = acc0;
  if      (wid == 0) apply_wave<0, 7>(SgH, fxT, fyP, SgW, lg, lr, acc);
  else if (wid == 1) apply_wave<7, 6>(SgH, fxT, fyP, SgW, lg, lr, acc);
  else if (wid == 2) apply_wave<13, 6>(SgH, fxT, fyP, SgW, lg, lr, acc);
  else               apply_wave<19, 6>(SgH, fxT, fyP, SgW, lg, lr, acc);
  const float* invqH = invn + (b * 8 + hd) * 80;                 // H_fy(q)
  const float* invqW = invn + 2 * Nb * 640 + (b * 8 + hd) * 80;  // W_fx(q)
  int t0  = wid ? 6 * wid + 1 : 0;
  int cnt = wid ? 6 : 7;
  #pragma unroll
  for (int j = 0; j < 7; j++) {
    if (j < cnt) {
      int tt = t0 + j, m = tt / 5, n = tt % 5;
      int col = n * 16 + lr;
      float ivW = invqW[col];
      #pragma unroll
      for (int r = 0; r < 4; r++) {
        int row = m * 16 + 4 * lg + r;
        size_t ix = off + row * 80 + col;
        float v = acc[j][r] + b2f(fy_g[ix]) * invqH[row] + b2f(fx_io[ix]) * ivW;
        fx_io[ix] = f2b(v);
      }
    }
  }
}

extern "C" void kernel_launch(void* const* d_in, const int* in_sizes, int n_in,
                              void* d_out, int out_size, void* d_ws, size_t ws_size,
                              hipStream_t stream) {
  // Weight conversion table: d_in[1..18] in setup_inputs order.
  const int wsz[18] = {256, 256, 65536, 256, 65536, 256,
                       1792, 256, 2816, 256, 5376, 256,
                       1792, 256, 2816, 256, 5376, 256};
  CvtArgs ca;
  int cum = 0;
  for (int i = 0; i < 18; i++) { ca.src[i] = d_in[i + 1]; ca.cum[i] = cum; cum += wsz[i]; }
  ca.cum[18] = cum;   // 153600

  // Host-side dtype detection: x (and out) have 26,214,400 elements, so
  // 104857600 bytes => f32, 52428800 => bf16. Try in_sizes[0] AND out_size.
  // Fall back to the fast device probe only if neither matches.
  int hostf = -1;
  if (in_sizes && n_in > 0) {
    if      (in_sizes[0] == 104857600) hostf = 1;
    else if (in_sizes[0] == 52428800)  hostf = 0;
  }
  if (hostf < 0) {
    if      (out_size == 104857600) hostf = 1;
    else if (out_size == 52428800)  hostf = 0;
  }

  // ws layout: flag(16) | wbuf(614400) | wsplit(524288) | per-chunk buffers.
  int Nb = 1;
  for (int cand = 16; cand >= 1; cand >>= 1) {
    size_t need = (size_t)cand * 13701120 + 614416 + 524288;
    if (need <= ws_size) { Nb = cand; break; }
  }
  char* p = (char*)d_ws;
  int*    flag  = (int*)p;    p += 16;
  float*  wbuf  = (float*)p;  p += 614400;
  u16*    wsplit= (u16*)p;    p += 524288;     // [2 mat][2 set][256][256] bf16
  u16*    fxbuf = (u16*)p;    p += (size_t)Nb * 3276800;
  u16*    fybuf = (u16*)p;    p += (size_t)Nb * 3276800;
  u16*    fxT   = (u16*)p;    p += (size_t)Nb * 3276800;
  u16*    fyT   = (u16*)p;    p += (size_t)Nb * 3276800;
  float2* stats = (float2*)p; p += (size_t)Nb * 51200;
  float*  rs_fx = (float*)p;  p += (size_t)Nb * 81920;
  float*  rs_fy = (float*)p;  p += (size_t)Nb * 81920;
  float*  cs_fx = (float*)p;  p += (size_t)Nb * 81920;
  float*  cs_fy = (float*)p;  p += (size_t)Nb * 81920;
  float*  invn  = (float*)p;  p += (size_t)Nb * 10240;
  u16*    Sbuf  = (u16*)p;

  // f32 weight views
  float* ln_g = wbuf + ca.cum[0];  float* ln_b = wbuf + ca.cum[1];
  float* w_in = wbuf + ca.cum[2];  float* b_in = wbuf + ca.cum[3];
  float* w_out= wbuf + ca.cum[4]; float* b_out= wbuf + ca.cum[5];
  float* wx7  = wbuf + ca.cum[6];  float* bx7  = wbuf + ca.cum[7];
  float* wx11 = wbuf + ca.cum[8];  float* bx11 = wbuf + ca.cum[9];
  float* wx21 = wbuf + ca.cum[10]; float* bx21 = wbuf + ca.cum[11];
  float* wy7  = wbuf + ca.cum[12]; float* by7  = wbuf + ca.cum[13];
  float* wy11 = wbuf + ca.cum[14]; float* by11 = wbuf + ca.cum[15];
  float* wy21 = wbuf + ca.cum[16]; float* by21 = wbuf + ca.cum[17];

  if (hostf < 0) {
    probe_init<<<dim3(1), dim3(1), 0, stream>>>(flag);
    probe_count<<<dim3(64), dim3(256), 0, stream>>>((const u16*)d_in[0], flag);
    probe_decide<<<dim3(1), dim3(1), 0, stream>>>(flag);
  }
  cvt_weights<<<dim3(600), dim3(256), 0, stream>>>(ca, wbuf, hostf, flag);
  split_w<<<dim3(512), dim3(256), 0, stream>>>(w_in, w_out, wsplit);

  for (int b0 = 0; b0 < NB; b0 += Nb) {
    size_t xoff = (size_t)b0 * NC * NHW;   // element offset of chunk in x / out

    ln_stats<<<dim3(7, Nb), dim3(256), 0, stream>>>(d_in[0], xoff, hostf, flag, stats);
    dw_both<<<dim3(Nb * 256), dim3(256), 0, stream>>>(d_in[0], xoff, hostf, flag, stats,
        ln_g, ln_b, wx7, bx7, wx11, bx11, wx21, bx21,
        wy7, by7, wy11, by11, wy21, by21, fxbuf, fybuf);
    pw_mfma_t<0><<<dim3(100, Nb, 2), dim3(256), 0, stream>>>(wsplit, fxbuf, fybuf,
        b_in, nullptr, 0, nullptr, 0, hostf, flag);
    transpose_sumsq<<<dim3(Nb * 256, 2), dim3(256), 0, stream>>>(fxbuf, fybuf, fxT, fyT,
        rs_fx, rs_fy, cs_fx, cs_fy);
    norm_combine<<<dim3(10 * Nb), dim3(256), 0, stream>>>(rs_fx, rs_fy, cs_fx, cs_fy, invn, Nb);
    gram_softmax_mfma<<<dim3(8, Nb, 2), dim3(256), 0, stream>>>(fxbuf, fybuf, fxT, fyT, invn, Sbuf, Nb);
    apply_hw_mfma<<<dim3(32, 8, Nb), dim3(256), 0, stream>>>(fybuf, fxT, Sbuf, invn, fxbuf, Nb);
    pw_mfma_t<1><<<dim3(100, Nb, 1), dim3(256), 0, stream>>>(wsplit + 131072, fxbuf, nullptr,
        b_out, d_out, xoff, d_in[0], xoff, hostf, flag);
  }
  (void)in_sizes; (void)n_in; (void)out_size;
}

// Round 9
// 864.381 us; speedup vs baseline: 1.2450x; 1.0230x over previous
//
#include <hip/hip_runtime.h>

typedef unsigned short u16;
typedef unsigned int   u32;

#define NB  16
#define NC  256
#define NH  80
#define NW  80
#define NHW 6400

typedef short bf16x8 __attribute__((ext_vector_type(8)));
typedef float f32x4  __attribute__((ext_vector_type(4)));

__device__ __forceinline__ float b2f(u16 u) {
  union { u32 i; float f; } c; c.i = ((u32)u) << 16; return c.f;
}
__device__ __forceinline__ u16 f2b(float f) {
  union { float f; u32 i; } c; c.f = f;
  return (u16)((c.i + 0x7FFFu + ((c.i >> 16) & 1u)) >> 16);
}
// dtype-dispatched input load (flag=1: f32, flag=0: bf16)
__device__ __forceinline__ float ldx(const void* p, size_t i, int f32f) {
  return f32f ? ((const float*)p)[i] : b2f(((const u16*)p)[i]);
}
// resolve dtype flag: host-decided (fh>=0) or device-probed fallback
__device__ __forceinline__ int getf(int fh, const int* flagp) {
  return (fh >= 0) ? fh : *flagp;
}

// ---- K0a (fallback only): fast parallel dtype probe ----
__global__ void probe_init(int* __restrict__ flag) { flag[0] = 0; flag[1] = 0; }

__global__ __launch_bounds__(256) void probe_count(const u16* __restrict__ x,
                                                   int* __restrict__ flag)
{
  __shared__ int cnt[256];
  int base = (blockIdx.x * 256 + threadIdx.x) * 16;   // 64*256*16 = 262144
  int c = 0;
  uint4 v0 = *(const uint4*)(x + base);
  uint4 v1 = *(const uint4*)(x + base + 8);
  u32 w[8] = {v0.x, v0.y, v0.z, v0.w, v1.x, v1.y, v1.z, v1.w};
  #pragma unroll
  for (int j = 0; j < 8; j++) {
    if (((w[j] >> 7)  & 0xFFu) == 0xFFu) c++;
    if (((w[j] >> 23) & 0xFFu) == 0xFFu) c++;
  }
  cnt[threadIdx.x] = c; __syncthreads();
  for (int s = 128; s > 0; s >>= 1) {
    if (threadIdx.x < s) cnt[threadIdx.x] += cnt[threadIdx.x + s];
    __syncthreads();
  }
  if (threadIdx.x == 0) atomicAdd(&flag[1], cnt[0]);
}

__global__ void probe_decide(int* __restrict__ flag) {
  flag[0] = (flag[1] > 16) ? 1 : 0;
}

// ---- K0b: convert all 18 weight/bias arrays into one f32 table ----
struct CvtArgs { const void* src[18]; int cum[19]; };

__global__ __launch_bounds__(256) void cvt_weights(CvtArgs a, float* __restrict__ dst,
                                                   int fh, const int* __restrict__ flagp)
{
  int f = getf(fh, flagp);
  int i = blockIdx.x * 256 + threadIdx.x;     // < 153600
  int s = 0;
  while (i >= a.cum[s + 1]) s++;
  int j = i - a.cum[s];
  float v = f ? ((const float*)a.src[s])[j] : b2f(((const u16*)a.src[s])[j]);
  if (!(v == v) || fabsf(v) > 1e30f) v = 0.f;  // scrub
  dst[i] = v;
}

// ---- K0c: split w_in / w_out into bf16 hi+lo pairs for MFMA.
// WB layout: [mat][set][256 o][256 k] u16, mat stride 131072, set stride 65536.
__global__ __launch_bounds__(256) void split_w(const float* __restrict__ w_in,
    const float* __restrict__ w_out, u16* __restrict__ WB)
{
  int i = blockIdx.x * 256 + threadIdx.x;   // < 131072
  int mat = i >> 16, idx = i & 65535;
  float v = (mat ? w_out : w_in)[idx];
  u16 hi = f2b(v);
  u16 lo = f2b(v - b2f(hi));
  WB[mat * 131072 + idx] = hi;
  WB[mat * 131072 + 65536 + idx] = lo;
}

// ---- K1: per-pixel LN stats (mean, rstd) over C; 4 px/thread vectorized ----
__global__ __launch_bounds__(256) void ln_stats(const void* __restrict__ xsrc,
    size_t xoff, int fh, const int* __restrict__ flagp, float2* __restrict__ stats)
{
  int f = getf(fh, flagp);
  int bl = blockIdx.y;
  int p4 = blockIdx.x * 1024 + threadIdx.x * 4;
  if (p4 >= NHW) return;                       // last block covers 256 px only
  size_t base = xoff + (size_t)bl * NC * NHW + p4;
  float s1[4] = {0.f, 0.f, 0.f, 0.f}, s2[4] = {0.f, 0.f, 0.f, 0.f};
  if (f) {
    const float* xp = (const float*)xsrc + base;
    for (int c = 0; c < NC; c++) {
      float4 v = *(const float4*)(xp + (size_t)c * NHW);
      s1[0] += v.x; s2[0] += v.x * v.x;
      s1[1] += v.y; s2[1] += v.y * v.y;
      s1[2] += v.z; s2[2] += v.z * v.z;
      s1[3] += v.w; s2[3] += v.w * v.w;
    }
  } else {
    const u16* xp = (const u16*)xsrc + base;
    for (int c = 0; c < NC; c++) {
      ushort4 v = *(const ushort4*)(xp + (size_t)c * NHW);
      float a = b2f(v.x), b = b2f(v.y), cc = b2f(v.z), d = b2f(v.w);
      s1[0] += a;  s2[0] += a * a;
      s1[1] += b;  s2[1] += b * b;
      s1[2] += cc; s2[2] += cc * cc;
      s1[3] += d;  s2[3] += d * d;
    }
  }
  float2* so = stats + (size_t)bl * NHW + p4;
  #pragma unroll
  for (int j = 0; j < 4; j++) {
    float mean = s1[j] * (1.f / 256.f);
    float var  = s2[j] * (1.f / 256.f) - mean * mean;
    so[j] = make_float2(mean, rsqrtf(var + 1e-5f));
  }
}

// ---- K2: fused LN + BOTH depthwise convs, register-blocked stencil ----
__global__ __launch_bounds__(256) void dw_both(const void* __restrict__ xsrc,
    size_t xoff, int fh, const int* __restrict__ flagp,
    const float2* __restrict__ stats,
    const float* __restrict__ g, const float* __restrict__ bt,
    const float* __restrict__ wx7,  const float* __restrict__ bx7,
    const float* __restrict__ wx11, const float* __restrict__ bx11,
    const float* __restrict__ wx21, const float* __restrict__ bx21,
    const float* __restrict__ wy7,  const float* __restrict__ by7,
    const float* __restrict__ wy11, const float* __restrict__ by11,
    const float* __restrict__ wy21, const float* __restrict__ by21,
    u16* __restrict__ sx, u16* __restrict__ sy)
{
  __shared__ float xnp[80][116];        // cols 0..15 & 96..111 zero halo
  __shared__ float cwx[21], cwy[21];
  __shared__ float cbs[2];
  int f = getf(fh, flagp);
  int bc = blockIdx.x;                  // bl*256 + c
  int c  = bc & 255;
  int bl = bc >> 8;
  int t = threadIdx.x;
  if (t < 21) {
    float v = wx21[c * 21 + t];
    if (t >= 5 && t <= 15) v += wx11[c * 11 + t - 5];
    if (t >= 7 && t <= 13) v += wx7[c * 7 + t - 7];
    cwx[t] = v;
  } else if (t < 42) {
    int j = t - 21;
    float v = wy21[c * 21 + j];
    if (j >= 5 && j <= 15) v += wy11[c * 11 + j - 5];
    if (j >= 7 && j <= 13) v += wy7[c * 7 + j - 7];
    cwy[j] = v;
  } else if (t == 42) { cbs[0] = bx7[c] + bx11[c] + bx21[c]; }
  else if (t == 43)   { cbs[1] = by7[c] + by11[c] + by21[c]; }
  // zero halo columns (80 rows x 32 cols)
  for (int i = t; i < 2560; i += 256) {
    int rr = i >> 5, cc = i & 31;
    xnp[rr][cc < 16 ? cc : 80 + cc] = 0.f;
  }
  float cg = g[c], cbt = bt[c];
  size_t xrow = xoff + (size_t)bc * NHW;
  const float2* st = stats + (size_t)bl * NHW;
  for (int i = t; i < NHW; i += 256) {
    float v = ldx(xsrc, xrow + i, f);
    float2 s = st[i];
    xnp[i / 80][16 + i % 80] = (v - s.x) * s.y * cg + cbt;
  }
  __syncthreads();
  float bxv = cbs[0], byv = cbs[1];
  size_t obase = (size_t)bc * NHW;
  for (int u = t; u < 800; u += 256) {  // 3 full rounds + 32-thread tail
    int h = u / 10, w0 = (u % 10) * 8;
    float r[32];
    #pragma unroll
    for (int j = 0; j < 8; j++)
      *(float4*)&r[4 * j] = *(const float4*)&xnp[h][w0 + 4 + 4 * j];
    float ax[8], ay[8];
    #pragma unroll
    for (int j = 0; j < 8; j++) { ax[j] = bxv; ay[j] = byv; }
    #pragma unroll
    for (int dd = 0; dd < 21; dd++) {
      float wv = cwx[dd];
      #pragma unroll
      for (int j = 0; j < 8; j++) ax[j] += wv * r[j + 2 + dd];
    }
    #pragma unroll
    for (int dd = 0; dd < 21; dd++) {
      int hp = h + dd - 10;
      int hc = min(max(hp, 0), 79);
      float wv = (hp == hc) ? cwy[dd] : 0.f;
      float4 v0 = *(const float4*)&xnp[hc][16 + w0];
      float4 v1 = *(const float4*)&xnp[hc][20 + w0];
      ay[0] += wv * v0.x; ay[1] += wv * v0.y; ay[2] += wv * v0.z; ay[3] += wv * v0.w;
      ay[4] += wv * v1.x; ay[5] += wv * v1.y; ay[6] += wv * v1.z; ay[7] += wv * v1.w;
    }
    size_t ob = obase + h * 80 + w0;
    ushort4 a0, a1, b0, b1;
    a0.x = f2b(ax[0]); a0.y = f2b(ax[1]); a0.z = f2b(ax[2]); a0.w = f2b(ax[3]);
    a1.x = f2b(ax[4]); a1.y = f2b(ax[5]); a1.z = f2b(ax[6]); a1.w = f2b(ax[7]);
    b0.x = f2b(ay[0]); b0.y = f2b(ay[1]); b0.z = f2b(ay[2]); b0.w = f2b(ay[3]);
    b1.x = f2b(ay[4]); b1.y = f2b(ay[5]); b1.z = f2b(ay[6]); b1.w = f2b(ay[7]);
    *(ushort4*)(sx + ob)     = a0;
    *(ushort4*)(sx + ob + 4) = a1;
    *(ushort4*)(sy + ob)     = b0;
    *(ushort4*)(sy + ob + 4) = b1;
  }
}

// ---- K3/K8: MFMA pointwise conv, 128-px (256 B) tiles.
// Round-9: px tile widened 64->128 (HBM granule/XCD-locality fix: rounds 5-8
// all showed hbm_bytes ~2x algorithmic with 128B strips). K consumed in two
// 32 KB LDS passes InT[128px][128k], swizzle u = (k>>3) ^ (((px>>3)^px)&15).
// FINAL=0: [256 o] per block, IN-PLACE (self-contained: reads all k, writes
//          all o of its strip). acc[4][8].
// FINAL=1: [128 o] per block (o-split is race-free: writes d_out), acc[2][8],
//          4 waves/SIMD. 1-D grid with bijective XCD-chunk swizzle pairs the
//          two o-halves of a strip on one XCD so the 2nd In read L2-hits.
template<int FINAL>
__global__ __launch_bounds__(256) void pw_mfma_t(const u16* __restrict__ WB,
    u16* io0, u16* io1, const float* __restrict__ bias,
    void* __restrict__ OutBase, size_t out_off,
    const void* __restrict__ xsrc, size_t xoff,
    int fh, const int* __restrict__ flagp, int Nb, int chunk)
{
  __shared__ u16 S[16384];              // 32 KB: InT / epilogue tile
  constexpr int MT = FINAL ? 2 : 4;
  int d = blockIdx.x;
  int w = chunk ? (d & 7) * chunk + (d >> 3) : d;   // XCD-chunked remap
  int oh, px, bl, zz;
  if (FINAL) {
    oh = w & 1; int s = w >> 1; px = s % 50; bl = s / 50; zz = 0;
  } else {
    oh = 0; px = w % 50; int q = w / 50; bl = q % Nb; zz = q / Nb;
  }
  int p0 = px * 128;
  int t  = threadIdx.x;
  int lane = t & 63, wid = t >> 6, lg = lane >> 4, lr = lane & 15;
  u16* io = (FINAL || zz == 0) ? io0 : io1;

  f32x4 acc[MT][8];
  #pragma unroll
  for (int m = 0; m < MT; m++)
    #pragma unroll
    for (int n = 0; n < 8; n++)
      acc[m][n] = (f32x4){0.f, 0.f, 0.f, 0.f};

  for (int kh = 0; kh < 2; kh++) {
    if (kh) __syncthreads();            // prior pass's readers done
    {  // ---- stage InT[128px][128k] with register 8x8 transpose ----
      int kb = t >> 4, pb = t & 15;
      const u16* src = io + ((size_t)bl * NC + kh * 128 + kb * 8) * NHW + p0 + pb * 8;
      u32 r[8][4];
      #pragma unroll
      for (int i = 0; i < 8; i++) {
        uint4 v = *(const uint4*)(src + (size_t)i * NHW);
        r[i][0] = v.x; r[i][1] = v.y; r[i][2] = v.z; r[i][3] = v.w;
      }
      #pragma unroll
      for (int j = 0; j < 8; j++) {
        u32 wv[4];
        #pragma unroll
        for (int m = 0; m < 4; m++) {
          u32 a = r[2 * m][j >> 1], b = r[2 * m + 1][j >> 1];
          wv[m] = (j & 1) ? ((a >> 16) | (b & 0xFFFF0000u))
                          : ((a & 0xFFFFu) | (b << 16));
        }
        int pp = pb * 8 + j;
        int gg = ((pp >> 3) ^ pp) & 15;
        *(uint4*)&S[pp * 128 + ((kb ^ gg) & 15) * 8] = make_uint4(wv[0], wv[1], wv[2], wv[3]);
      }
    }
    __syncthreads();
    #pragma unroll
    for (int chl = 0; chl < 4; chl++) {
      int kglob = kh * 128 + chl * 32;
      #pragma unroll
      for (int m = 0; m < MT; m++) {
        int o = (FINAL ? oh * 128 : 0) + (wid * MT + m) * 16 + lr;
        const u16* wrow = WB + (size_t)o * 256 + kglob + lg * 8;
        bf16x8 ahi = *(const bf16x8*)(wrow);
        bf16x8 alo = *(const bf16x8*)(wrow + 65536);
        #pragma unroll
        for (int ng = 0; ng < 4; ng++) {
          int pxa = (ng * 2) * 16 + lr, pxb = pxa + 16;
          int ka = chl * 4 + lg;
          bf16x8 b0 = *(const bf16x8*)&S[pxa * 128 + ((ka ^ (((pxa >> 3) ^ pxa) & 15)) & 15) * 8];
          bf16x8 b1 = *(const bf16x8*)&S[pxb * 128 + ((ka ^ (((pxb >> 3) ^ pxb) & 15)) & 15) * 8];
          acc[m][ng * 2]     = __builtin_amdgcn_mfma_f32_16x16x32_bf16(ahi, b0, acc[m][ng * 2], 0, 0, 0);
          acc[m][ng * 2]     = __builtin_amdgcn_mfma_f32_16x16x32_bf16(alo, b0, acc[m][ng * 2], 0, 0, 0);
          acc[m][ng * 2 + 1] = __builtin_amdgcn_mfma_f32_16x16x32_bf16(ahi, b1, acc[m][ng * 2 + 1], 0, 0, 0);
          acc[m][ng * 2 + 1] = __builtin_amdgcn_mfma_f32_16x16x32_bf16(alo, b1, acc[m][ng * 2 + 1], 0, 0, 0);
        }
      }
    }
  }
  __syncthreads();                       // all InT reads done before reuse

  if (FINAL) {
    // ---- [128 o][128 px] f32 through two 32 KB halves of 64 rows ----
    float* Otf = (float*)S;
    int f = getf(fh, flagp);
    #pragma unroll
    for (int h = 0; h < 2; h++) {
      if ((wid >> 1) == h) {
        #pragma unroll
        for (int m = 0; m < 2; m++)
          #pragma unroll
          for (int r = 0; r < 4; r++) {
            int ol = (wid * 2 + m) * 16 + 4 * lg + r;   // 0..127
            int ro = ol & 63;
            float bv = 2.f * bias[oh * 128 + ol];
            #pragma unroll
            for (int n = 0; n < 8; n++) {
              int pxn = n * 16 + lr;
              int cuf = (pxn >> 2) ^ (ro & 7);
              Otf[ro * 128 + cuf * 4 + (pxn & 3)] = acc[m][n][r] + bv;
            }
          }
      }
      __syncthreads();
      int row = t >> 2, q = t & 3;
      size_t gbase = ((size_t)bl * NC + oh * 128 + h * 64 + row) * NHW + p0 + q * 32;
      #pragma unroll
      for (int j = 0; j < 8; j++) {
        int uf = q * 8 + j;
        int cuf = uf ^ (row & 7);
        float4 v = *(float4*)&Otf[row * 128 + cuf * 4];
        size_t gi = gbase + j * 4;
        if (f) {
          const float* xp = (const float*)xsrc + xoff + gi;
          v.x += xp[0]; v.y += xp[1]; v.z += xp[2]; v.w += xp[3];
          *(float4*)((float*)OutBase + out_off + gi) = v;
        } else {
          ushort4 xv = *(const ushort4*)((const u16*)xsrc + xoff + gi);
          ushort4 ov;
          ov.x = f2b(v.x + b2f(xv.x)); ov.y = f2b(v.y + b2f(xv.y));
          ov.z = f2b(v.z + b2f(xv.z)); ov.w = f2b(v.w + b2f(xv.w));
          *(ushort4*)((u16*)OutBase + out_off + gi) = ov;
        }
      }
      __syncthreads();
    }
  } else {
    // ---- [256 o][128 px] u16 through two 32 KB halves of 128 rows ----
    u16* Ot = S;
    #pragma unroll
    for (int h = 0; h < 2; h++) {
      if ((wid >> 1) == h) {
        #pragma unroll
        for (int m = 0; m < 4; m++)
          #pragma unroll
          for (int r = 0; r < 4; r++) {
            int o  = (wid * 4 + m) * 16 + 4 * lg + r;    // 0..255
            int ol = o & 127;
            float bv = bias[o];
            #pragma unroll
            for (int n = 0; n < 8; n++) {
              int pxn = n * 16 + lr;
              int cu = ((pxn >> 3) + (ol & 7)) & 15;
              Ot[ol * 128 + cu * 8 + (pxn & 7)] = f2b(acc[m][n][r] + bv);
            }
          }
      }
      __syncthreads();
      int row = t >> 1, half = t & 1;
      u16* orow = io + ((size_t)bl * NC + h * 128 + row) * NHW + p0 + half * 64;
      #pragma unroll
      for (int j = 0; j < 8; j++) {
        int cu = ((half * 8 + j) + (row & 7)) & 15;
        *(uint4*)(orow + j * 8) = *(uint4*)&Ot[row * 128 + cu * 8];
      }
      __syncthreads();
    }
  }
  (void)OutBase; (void)out_off; (void)xsrc; (void)xoff; (void)flagp; (void)io1;
}

// ---- K-T fused: per-plane 80x80 bf16 transpose + row/col sum of squares ----
__global__ __launch_bounds__(256) void transpose_sumsq(const u16* __restrict__ fx,
    const u16* __restrict__ fy, u16* __restrict__ fxT, u16* __restrict__ fyT,
    float* __restrict__ rs_fx, float* __restrict__ rs_fy,
    float* __restrict__ cs_fx, float* __restrict__ cs_fy)
{
  __shared__ u16 tile[80][81];
  int pl = blockIdx.x, ten = blockIdx.y;
  const u16* src = (ten ? fy : fx) + (size_t)pl * NHW;
  u16*       dst = (ten ? fyT : fxT) + (size_t)pl * NHW;
  int t = threadIdx.x;
  for (int i = t; i < NHW; i += 256) tile[i / 80][i % 80] = src[i];
  __syncthreads();
  for (int i = t; i < NHW; i += 256) dst[i] = tile[i % 80][i / 80];
  if (t < 80) {
    float s = 0.f;
    #pragma unroll
    for (int k = 0; k < 80; k++) { float v = b2f(tile[t][k]); s += v * v; }
    (ten ? rs_fy : rs_fx)[pl * 80 + t] = s;
  } else if (t < 160) {
    int w = t - 80; float s = 0.f;
    #pragma unroll
    for (int h = 0; h < 80; h++) { float v = b2f(tile[h][w]); s += v * v; }
    (ten ? cs_fy : cs_fx)[pl * 80 + w] = s;
  }
}

// ---- K5: combine over ci -> inverse norms ----
__global__ __launch_bounds__(256) void norm_combine(const float* __restrict__ rs_fx,
    const float* __restrict__ rs_fy, const float* __restrict__ cs_fx,
    const float* __restrict__ cs_fy, float* __restrict__ invn, int Nb)
{
  int t = blockIdx.x * 256 + threadIdx.x;   // 4*Nb*640 total
  int blk = Nb * 640;
  int side = t / blk, r = t % blk;
  int b = r / 640, rem = r % 640, hd = rem / 80, row = rem % 80;
  const float* src = (side == 0) ? rs_fy : (side == 1) ? rs_fx : (side == 2) ? cs_fx : cs_fy;
  size_t base = (size_t)(b * 256 + hd * 32) * 80 + row;
  float s = 0.f;
  #pragma unroll
  for (int ci = 0; ci < 32; ci++) s += src[base + ci * 80];
  invn[t] = 1.f / fmaxf(sqrtf(s), 1e-12f);
}

// ---- MFMA helpers for 80x80 Gram-style tiles ----
template<int T0, int NT>
__device__ __forceinline__ void gram_wave(const u16* pa, const u16* pb,
                                          int lg, int lr, f32x4* acc)
{
  constexpr int MLO = T0 / 5;
  #pragma unroll
  for (int ch = 0; ch < 3; ch++) {
    bool tz = (ch == 2) && (lg >= 2);
    int kk = ch * 32 + 8 * lg;
    if (tz) kk = 0;
    bf16x8 af[2], bf[5];
    #pragma unroll
    for (int m = 0; m < 2; m++)
      af[m] = *(const bf16x8*)(pa + ((MLO + m) * 16 + lr) * 80 + kk);
    #pragma unroll
    for (int n = 0; n < 5; n++)
      bf[n] = *(const bf16x8*)(pb + (n * 16 + lr) * 80 + kk);
    if (tz) {
      bf16x8 z = {0, 0, 0, 0, 0, 0, 0, 0};
      af[0] = z; af[1] = z;
    }
    #pragma unroll
    for (int j = 0; j < NT; j++) {
      acc[j] = __builtin_amdgcn_mfma_f32_16x16x32_bf16(
          af[(T0 + j) / 5 - MLO], bf[(T0 + j) % 5], acc[j], 0, 0, 0);
    }
  }
}

template<int T0, int NT>
__device__ __forceinline__ void gram_all(const u16* Ab, const u16* Bb,
                                         int lg, int lr, f32x4* acc)
{
  for (int ci = 0; ci < 32; ci++)
    gram_wave<T0, NT>(Ab + (size_t)ci * NHW, Bb + (size_t)ci * NHW, lg, lr, acc);
}

// ---- K6: MFMA Gram (sum over 32 ci) + cosine scale + softmax -> Sbuf ----
__global__ __launch_bounds__(256) void gram_softmax_mfma(const u16* __restrict__ fx,
    const u16* __restrict__ fy, const u16* __restrict__ fxT, const u16* __restrict__ fyT,
    const float* __restrict__ invn, u16* __restrict__ Sbuf, int Nb)
{
  __shared__ float At[80][81];
  int hd = blockIdx.x, b = blockIdx.y, axis = blockIdx.z;
  size_t sl0 = (size_t)(b * 256 + hd * 32) * NHW;
  const u16* Ab = (axis ? fxT : fy) + sl0;
  const u16* Bb = (axis ? fyT : fx) + sl0;
  int t = threadIdx.x, lane = t & 63, wid = t >> 6;
  int lg = lane >> 4, lr = lane & 15;
  f32x4 acc0 = {0.f, 0.f, 0.f, 0.f};
  f32x4 acc[7];
  #pragma unroll
  for (int j = 0; j < 7; j++) acc[j] = acc0;
  if      (wid == 0) gram_all<0, 7>(Ab, Bb, lg, lr, acc);
  else if (wid == 1) gram_all<7, 6>(Ab, Bb, lg, lr, acc);
  else if (wid == 2) gram_all<13, 6>(Ab, Bb, lg, lr, acc);
  else               gram_all<19, 6>(Ab, Bb, lg, lr, acc);
  int blk = Nb * 640;
  int rowbase = (b * 8 + hd) * 80;
  const float* invq = invn + (axis ? 2 * blk : 0)   + rowbase;
  const float* invk = invn + (axis ? 3 * blk : blk) + rowbase;
  int t0  = wid ? 6 * wid + 1 : 0;
  int cnt = wid ? 6 : 7;
  #pragma unroll
  for (int j = 0; j < 7; j++) {
    if (j < cnt) {
      int tt = t0 + j, m = tt / 5, n = tt % 5;
      int col = n * 16 + lr;
      float ik = invk[col];
      #pragma unroll
      for (int r = 0; r < 4; r++) {
        int row = m * 16 + 4 * lg + r;
        float gv = acc[j][r] * invq[row] * ik;
        At[row][col] = fminf(fmaxf(gv, -8.f), 8.f);  // |cos|<=1; NaN->-8
      }
    }
  }
  __syncthreads();
  u16* Sg = Sbuf + ((size_t)(axis * Nb * 8 + b * 8 + hd)) * NHW;
  if (t < 80) {
    float mx = -1e30f;
    for (int j = 0; j < 80; j++) mx = fmaxf(mx, At[t][j]);
    float s = 0.f;
    for (int j = 0; j < 80; j++) s += __expf(At[t][j] - mx);
    float inv = 1.f / s;
    for (int j = 0; j < 80; j++) Sg[t * 80 + j] = f2b(__expf(At[t][j] - mx) * inv);
  }
}

// ---- K7: MFMA fused H+W attention apply, IN PLACE over fx slice ----
template<int T0, int NT>
__device__ __forceinline__ void apply_wave(const u16* SH, const u16* fxT,
    const u16* fyP, const u16* SW, int lg, int lr, f32x4* acc)
{
  constexpr int MLO = T0 / 5;
  for (int ch = 0; ch < 3; ch++) {
    bool tz = (ch == 2) && (lg >= 2);
    int kk = ch * 32 + 8 * lg;
    if (tz) kk = 0;
    bf16x8 a1[2], a2[2], b1[5], b2[5];
    #pragma unroll
    for (int m = 0; m < 2; m++) {
      a1[m] = *(const bf16x8*)(SH  + ((MLO + m) * 16 + lr) * 80 + kk);
      a2[m] = *(const bf16x8*)(fyP + ((MLO + m) * 16 + lr) * 80 + kk);
    }
    #pragma unroll
    for (int n = 0; n < 5; n++) {
      b1[n] = *(const bf16x8*)(fxT + (n * 16 + lr) * 80 + kk);
      b2[n] = *(const bf16x8*)(SW  + (n * 16 + lr) * 80 + kk);
    }
    if (tz) {
      bf16x8 z = {0, 0, 0, 0, 0, 0, 0, 0};
      a1[0] = z; a1[1] = z; a2[0] = z; a2[1] = z;
    }
    #pragma unroll
    for (int j = 0; j < NT; j++) {
      acc[j] = __builtin_amdgcn_mfma_f32_16x16x32_bf16(
          a1[(T0 + j) / 5 - MLO], b1[(T0 + j) % 5], acc[j], 0, 0, 0);
      acc[j] = __builtin_amdgcn_mfma_f32_16x16x32_bf16(
          a2[(T0 + j) / 5 - MLO], b2[(T0 + j) % 5], acc[j], 0, 0, 0);
    }
  }
}

__global__ __launch_bounds__(256, 2) void apply_hw_mfma(const u16* __restrict__ fy_g,
    const u16* __restrict__ fxT_g, const u16* __restrict__ Sbuf,
    const float* __restrict__ invn, u16* fx_io, int Nb)
{
  int ci = blockIdx.x, hd = blockIdx.y, b = blockIdx.z;
  size_t off = (size_t)(b * 256 + hd * 32 + ci) * NHW;
  const u16* SgH = Sbuf + (size_t)(b * 8 + hd) * NHW;
  const u16* SgW = Sbuf + ((size_t)(Nb * 8) + b * 8 + hd) * NHW;
  const u16* fyP = fy_g + off;
  const u16* fxT = fxT_g + off;
  int t = threadIdx.x, lane = t & 63, wid = t >> 6;
  int lg = lane >> 4, lr = lane & 15;
  f32x4 acc0 = {0.f, 0.f, 0.f, 0.f};
  f32x4 acc[7];
  #pragma unroll
  for (int j = 0; j < 7; j++) acc[j] = acc0;
  if      (wid == 0) apply_wave<0, 7>(SgH, fxT, fyP, SgW, lg, lr, acc);
  else if (wid == 1) apply_wave<7, 6>(SgH, fxT, fyP, SgW, lg, lr, acc);
  else if (wid == 2) apply_wave<13, 6>(SgH, fxT, fyP, SgW, lg, lr, acc);
  else               apply_wave<19, 6>(SgH, fxT, fyP, SgW, lg, lr, acc);
  const float* invqH = invn + (b * 8 + hd) * 80;                 // H_fy(q)
  const float* invqW = invn + 2 * Nb * 640 + (b * 8 + hd) * 80;  // W_fx(q)
  int t0  = wid ? 6 * wid + 1 : 0;
  int cnt = wid ? 6 : 7;
  #pragma unroll
  for (int j = 0; j < 7; j++) {
    if (j < cnt) {
      int tt = t0 + j, m = tt / 5, n = tt % 5;
      int col = n * 16 + lr;
      float ivW = invqW[col];
      #pragma unroll
      for (int r = 0; r < 4; r++) {
        int row = m * 16 + 4 * lg + r;
        size_t ix = off + row * 80 + col;
        float v = acc[j][r] + b2f(fy_g[ix]) * invqH[row] + b2f(fx_io[ix]) * ivW;
        fx_io[ix] = f2b(v);
      }
    }
  }
}

extern "C" void kernel_launch(void* const* d_in, const int* in_sizes, int n_in,
                              void* d_out, int out_size, void* d_ws, size_t ws_size,
                              hipStream_t stream) {
  // Weight conversion table: d_in[1..18] in setup_inputs order.
  const int wsz[18] = {256, 256, 65536, 256, 65536, 256,
                       1792, 256, 2816, 256, 5376, 256,
                       1792, 256, 2816, 256, 5376, 256};
  CvtArgs ca;
  int cum = 0;
  for (int i = 0; i < 18; i++) { ca.src[i] = d_in[i + 1]; ca.cum[i] = cum; cum += wsz[i]; }
  ca.cum[18] = cum;   // 153600

  // Host-side dtype detection: x (and out) have 26,214,400 elements.
  int hostf = -1;
  if (in_sizes && n_in > 0) {
    if      (in_sizes[0] == 104857600) hostf = 1;
    else if (in_sizes[0] == 52428800)  hostf = 0;
  }
  if (hostf < 0) {
    if      (out_size == 104857600) hostf = 1;
    else if (out_size == 52428800)  hostf = 0;
  }

  // ws layout: flag(16) | wbuf(614400) | wsplit(524288) | per-chunk buffers.
  int Nb = 1;
  for (int cand = 16; cand >= 1; cand >>= 1) {
    size_t need = (size_t)cand * 13701120 + 614416 + 524288;
    if (need <= ws_size) { Nb = cand; break; }
  }
  char* p = (char*)d_ws;
  int*    flag  = (int*)p;    p += 16;
  float*  wbuf  = (float*)p;  p += 614400;
  u16*    wsplit= (u16*)p;    p += 524288;     // [2 mat][2 set][256][256] bf16
  u16*    fxbuf = (u16*)p;    p += (size_t)Nb * 3276800;
  u16*    fybuf = (u16*)p;    p += (size_t)Nb * 3276800;
  u16*    fxT   = (u16*)p;    p += (size_t)Nb * 3276800;
  u16*    fyT   = (u16*)p;    p += (size_t)Nb * 3276800;
  float2* stats = (float2*)p; p += (size_t)Nb * 51200;
  float*  rs_fx = (float*)p;  p += (size_t)Nb * 81920;
  float*  rs_fy = (float*)p;  p += (size_t)Nb * 81920;
  float*  cs_fx = (float*)p;  p += (size_t)Nb * 81920;
  float*  cs_fy = (float*)p;  p += (size_t)Nb * 81920;
  float*  invn  = (float*)p;  p += (size_t)Nb * 10240;
  u16*    Sbuf  = (u16*)p;

  // f32 weight views
  float* ln_g = wbuf + ca.cum[0];  float* ln_b = wbuf + ca.cum[1];
  float* w_in = wbuf + ca.cum[2];  float* b_in = wbuf + ca.cum[3];
  float* w_out= wbuf + ca.cum[4]; float* b_out= wbuf + ca.cum[5];
  float* wx7  = wbuf + ca.cum[6];  float* bx7  = wbuf + ca.cum[7];
  float* wx11 = wbuf + ca.cum[8];  float* bx11 = wbuf + ca.cum[9];
  float* wx21 = wbuf + ca.cum[10]; float* bx21 = wbuf + ca.cum[11];
  float* wy7  = wbuf + ca.cum[12]; float* by7  = wbuf + ca.cum[13];
  float* wy11 = wbuf + ca.cum[14]; float* by11 = wbuf + ca.cum[15];
  float* wy21 = wbuf + ca.cum[16]; float* by21 = wbuf + ca.cum[17];

  if (hostf < 0) {
    probe_init<<<dim3(1), dim3(1), 0, stream>>>(flag);
    probe_count<<<dim3(64), dim3(256), 0, stream>>>((const u16*)d_in[0], flag);
    probe_decide<<<dim3(1), dim3(1), 0, stream>>>(flag);
  }
  cvt_weights<<<dim3(600), dim3(256), 0, stream>>>(ca, wbuf, hostf, flag);
  split_w<<<dim3(512), dim3(256), 0, stream>>>(w_in, w_out, wsplit);

  int Gpw = 100 * Nb;                       // grid for both pw variants
  int chunk = (Gpw % 8 == 0) ? Gpw / 8 : 0; // XCD-chunk size (0 = identity)

  for (int b0 = 0; b0 < NB; b0 += Nb) {
    size_t xoff = (size_t)b0 * NC * NHW;   // element offset of chunk in x / out

    ln_stats<<<dim3(7, Nb), dim3(256), 0, stream>>>(d_in[0], xoff, hostf, flag, stats);
    dw_both<<<dim3(Nb * 256), dim3(256), 0, stream>>>(d_in[0], xoff, hostf, flag, stats,
        ln_g, ln_b, wx7, bx7, wx11, bx11, wx21, bx21,
        wy7, by7, wy11, by11, wy21, by21, fxbuf, fybuf);
    pw_mfma_t<0><<<dim3(Gpw), dim3(256), 0, stream>>>(wsplit, fxbuf, fybuf,
        b_in, nullptr, 0, nullptr, 0, hostf, flag, Nb, chunk);
    transpose_sumsq<<<dim3(Nb * 256, 2), dim3(256), 0, stream>>>(fxbuf, fybuf, fxT, fyT,
        rs_fx, rs_fy, cs_fx, cs_fy);
    norm_combine<<<dim3(10 * Nb), dim3(256), 0, stream>>>(rs_fx, rs_fy, cs_fx, cs_fy, invn, Nb);
    gram_softmax_mfma<<<dim3(8, Nb, 2), dim3(256), 0, stream>>>(fxbuf, fybuf, fxT, fyT, invn, Sbuf, Nb);
    apply_hw_mfma<<<dim3(32, 8, Nb), dim3(256), 0, stream>>>(fybuf, fxT, Sbuf, invn, fxbuf, Nb);
    pw_mfma_t<1><<<dim3(Gpw), dim3(256), 0, stream>>>(wsplit + 131072, fxbuf, nullptr,
        b_out, d_out, xoff, d_in[0], xoff, hostf, flag, Nb, chunk);
  }
  (void)in_sizes; (void)n_in; (void)out_size;
}